// Round 6
// baseline (360.342 us; speedup 1.0000x reference)
//
#include <hip/hip_runtime.h>
#include <stdint.h>

typedef unsigned short u16;
using short8 = __attribute__((ext_vector_type(8))) short;
using f32x4  = __attribute__((ext_vector_type(4))) float;

#define NB 4
#define NN 128
#define NF 32
#define ND 64
#define NMAT (NB*ND*NN*NN)   // 4,194,304

// ---- workspace byte offsets ----
#define OFF_A     0u           // fp32 [4][16384]
#define OFF_ACC   262144u      // fp32 [4] (+pad)
#define OFF_AAT   262400u      // fp32 [4][16384]
#define OFF_RA    524544u      // fp32 [4][128]
#define OFF_W     526592u      // fp32 [2][1152][64]
#define OFF_RM    1116416u     // fp32 [4][64][128]
#define OFF_CM    1247488u
#define OFF_RX    1378560u
#define OFF_CX    1509632u
#define OFF_FLAG  1640704u     // int (+pad)
#define OFF_BF    1640960u     // fp32 128 (+pad)
#define OFF_ATB   1641472u     // bf16 [4][128n][128k]  (A^T, k-contig)
#define OFF_WB    1772544u     // bf16 [2][10][64e][64d]
#define OFF_X2    1936384u     // bf16 NMAT   (aliases UAT)
#define OFF_XT    10324992u    // bf16 [4][16384 ij][64 d]  (aliases UBT)
#define OFF_UA    18713600u    // bf16 NMAT
#define OFF_UB    27102208u
#define OFF_UC    35490816u
#define OFF_UD    43879424u
#define OFF_YACC  52268032u    // fp32 NMAT  (end 69,045,248)
// convert scratch aliased INTO Yacc region (dead before first Yacc write):
#define OFF_XF    (OFF_YACC)            // fp32 16384
#define OFF_EWF   (OFF_YACC + 65536u)   // fp32 8192
#define OFF_CF    (OFF_YACC + 98304u)   // fp32 2*81920
#define OFF_UAT   OFF_X2
#define OFF_UBT   OFF_XT

__device__ __forceinline__ float b2f(u16 v){
  union { uint32_t u; float f; } x; x.u = ((uint32_t)v) << 16; return x.f;
}
__device__ __forceinline__ u16 f2b(float f){
  union { uint32_t u; float f2; } x; x.f2 = f;
  uint32_t u = x.u;
  return (u16)((u + 0x7FFFu + ((u >> 16) & 1u)) >> 16);
}

#define MFMA16(a,b,c) __builtin_amdgcn_mfma_f32_16x16x32_bf16((a),(b),(c),0,0,0)

__device__ __constant__ signed char dR1[18] = {0,9,1,10,2,3,4,13,14,19,5,7,15,18,6,8,16,17};
__device__ __constant__ signed char dR2[18] = {-1,11,-1,12,-1,-1,-1,-1,-1,-1,-1,-1,-1,-1,-1,-1,-1,-1};

// ---- dtype detect (kept for robustness) ----
__global__ void k_detect(const u16* __restrict__ x16, int* __restrict__ flag){
  int t = threadIdx.x;
  int hit = 0;
  for (int k = t; k < 16384; k += 256){
    u16 u = x16[k];
    int e = (u >> 7) & 0xFF;
    if (e >= 0x90) hit = 1;
  }
  if (hit) atomicOr(flag, 1);
}

__global__ void k_convert(const void* __restrict__ xs, const void* __restrict__ ews,
                          const void* __restrict__ c1s, const void* __restrict__ c2s,
                          const void* __restrict__ b1s, const void* __restrict__ b2s,
                          const int* __restrict__ flag,
                          float* __restrict__ xf, float* __restrict__ ewf,
                          float* __restrict__ cf, float* __restrict__ bfv){
  int t = blockIdx.x*256 + threadIdx.x;
  if (t >= 188544) return;
  int isf = *flag;
  const void* src; int idx; float* dst;
  if (t < 16384)      { src = xs;  idx = t;          dst = xf + idx; }
  else if (t < 24576) { src = ews; idx = t - 16384;  dst = ewf + idx; }
  else if (t < 106496){ src = c1s; idx = t - 24576;  dst = cf + idx; }
  else if (t < 188416){ src = c2s; idx = t - 106496; dst = cf + 81920 + idx; }
  else if (t < 188480){ src = b1s; idx = t - 188416; dst = bfv + idx; }
  else                { src = b2s; idx = t - 188480; dst = bfv + 64 + idx; }
  float v = isf ? ((const float*)src)[idx] : b2f(((const u16*)src)[idx]);
  *dst = v;
}

__global__ void k_scatter(const int* __restrict__ ei, const int* __restrict__ bat,
                          const float* __restrict__ ew, float* __restrict__ A, int E){
  int t = blockIdx.x*256 + threadIdx.x;
  if (t >= E) return;
  int s = ei[t], dnode = ei[E + t];
  int g = bat[s];
  int r = s - g*NN, c = dnode - g*NN;
  atomicAdd(&A[(g*NN + r)*NN + c], ew[t]);
}

__global__ void k_rA(const float* __restrict__ A, float* __restrict__ rA){
  int b = blockIdx.x, i = threadIdx.x;
  const float* Ab = A + (b*NN + i)*NN;
  float s = 0.f;
  for (int j = 0; j < NN; j++) s += Ab[j];
  rA[b*NN + i] = s;
}

__global__ __launch_bounds__(256) void k_AAt(const float* __restrict__ A, float* __restrict__ AAt){
  int b = blockIdx.y, iq = blockIdx.x;
  int t = threadIdx.x;
  int j = t & 127, ih = t >> 7;
  const float* Ab = A + b*NN*NN;
  float acc[8] = {0,0,0,0,0,0,0,0};
  for (int k = 0; k < NN; k++){
    float aj = Ab[j*NN + k];
    #pragma unroll
    for (int ii = 0; ii < 8; ii++){
      int i = iq*16 + ih*8 + ii;
      acc[ii] += Ab[i*NN + k] * aj;
    }
  }
  #pragma unroll
  for (int ii = 0; ii < 8; ii++){
    int i = iq*16 + ih*8 + ii;
    AAt[(b*NN + i)*NN + j] = acc[ii];
  }
}

// ---- ATb[b][n][k] = bf16(A[b][k][n]) ----
__global__ __launch_bounds__(256) void k_at(const float* __restrict__ A, u16* __restrict__ ATb){
  int b = blockIdx.x;
  __shared__ float lds[128][129];
  int t = threadIdx.x;
  for (int l = 0; l < 64; l++){
    int idx = l*256 + t;
    lds[idx >> 7][idx & 127] = A[b*16384 + idx];
  }
  __syncthreads();
  for (int l = 0; l < 64; l++){
    int idx = l*256 + t;
    int r = idx >> 7, c = idx & 127;
    ATb[b*16384 + idx] = f2b(lds[c][r]);
  }
}

// ---- layer-1 Xt[b][ij][d] directly from x ----
__global__ void k_makeXt1(const float* __restrict__ xf, u16* __restrict__ Xt){
  int idx = blockIdx.x*256 + threadIdx.x;
  if (idx >= NMAT) return;
  int d = idx & 63, ij = (idx >> 6) & 16383, b = idx >> 20;
  int i = ij >> 7, j = ij & 127;
  float v = (d < NF) ? xf[(b*NN + i)*NF + d] : xf[(b*NN + j)*NF + (d - NF)];
  Xt[idx] = f2b(v);
}

// ---- X[b][e][ij] -> Xt[b][ij][e] via LDS tiles ----
__global__ __launch_bounds__(256) void k_xt(const u16* __restrict__ X, u16* __restrict__ Xt){
  int b = blockIdx.y;
  int ij0 = blockIdx.x*64;
  __shared__ u16 lds[64][65];
  int t = threadIdx.x;
  #pragma unroll
  for (int l = 0; l < 2; l++){
    int idx = l*2048 + t*8;
    int d = idx >> 6, c = idx & 63;
    const u16* p = X + ((size_t)(b*64 + d))*16384 + ij0 + c;
    short8 v = *(const short8*)p;
    #pragma unroll
    for (int k = 0; k < 8; k++) lds[d][c + k] = (u16)v[k];
  }
  __syncthreads();
  #pragma unroll
  for (int l = 0; l < 2; l++){
    int idx = l*2048 + t*8;
    int r = idx >> 6, c = idx & 63;
    short8 v;
    #pragma unroll
    for (int k = 0; k < 8; k++) v[k] = (short)lds[c + k][r];
    *(short8*)(Xt + ((size_t)(b*16384 + ij0 + r))*64 + c) = v;
  }
}

// ---- per-be 128x128 transpose: Ua->UaT, Ub->UbT (out of place) ----
__global__ __launch_bounds__(256) void k_ut(const u16* __restrict__ Ua, const u16* __restrict__ Ub,
                                            u16* __restrict__ UaT, u16* __restrict__ UbT){
  int be = blockIdx.x;
  const u16* src = blockIdx.y ? Ub : Ua;
  u16* dst = blockIdx.y ? UbT : UaT;
  src += ((size_t)be) << 14; dst += ((size_t)be) << 14;
  __shared__ u16 lds[128][129];
  int t = threadIdx.x;
  #pragma unroll
  for (int l = 0; l < 8; l++){
    int idx = l*2048 + t*8;
    int r = idx >> 7, c = idx & 127;
    short8 v = *(const short8*)(src + r*128 + c);
    #pragma unroll
    for (int k = 0; k < 8; k++) lds[r][c + k] = (u16)v[k];
  }
  __syncthreads();
  #pragma unroll
  for (int l = 0; l < 8; l++){
    int idx = l*2048 + t*8;
    int r = idx >> 7, c = idx & 127;
    short8 v;
    #pragma unroll
    for (int k = 0; k < 8; k++) v[k] = (short)lds[c + k][r];
    *(short8*)(dst + r*128 + c) = v;
  }
}

// ---- W fp32 + bf16 Wb[L][slot<10][e][d] ----
__global__ void k_buildW(const float* __restrict__ cf, float* __restrict__ W, u16* __restrict__ Wb){
  int gl = blockIdx.x*256 + threadIdx.x;
  if (gl >= 2*1152*64) return;
  int L = gl / (1152*64);
  int rem = gl - L*1152*64;
  int row = rem >> 6, e = rem & 63;
  int slot = row >> 6, d = row & 63;
  const float* cc = cf + L*81920;
  int base = (d*64 + e)*20;
  float v = cc[base + dR1[slot]];
  if (dR2[slot] >= 0) v += cc[base + dR2[slot]];
  float scale = (slot == 9) ? 1.0f : (1.0f/128.0f);
  v *= scale;
  W[gl] = v;
  if (slot < 10)
    Wb[(((size_t)L*10 + slot)*64 + e)*64 + d] = f2b(v);
}

// ---- row/col sums of M=X*A and X ----
__global__ __launch_bounds__(256) void k_rowcol(const u16* __restrict__ Xt, const float* __restrict__ A,
                         float* __restrict__ RM, float* __restrict__ CM,
                         float* __restrict__ RX, float* __restrict__ CXv){
  int b = blockIdx.y;
  int t = threadIdx.x;
  int d = t & 63;
  int task = blockIdx.x*4 + (t >> 6);
  float sm = 0.f, sx = 0.f;
  if (task < 128){
    int i = task;
    for (int j = 0; j < 128; j++){
      float xv = b2f(Xt[((size_t)(b*16384 + i*128 + j))*64 + d]);
      float av = A[b*16384 + i*128 + j];
      sm += xv*av; sx += xv;
    }
    RM[(b*64 + d)*128 + i] = sm;
    RX[(b*64 + d)*128 + i] = sx;
  } else {
    int j = task - 128;
    for (int i = 0; i < 128; i++){
      float xv = b2f(Xt[((size_t)(b*16384 + i*128 + j))*64 + d]);
      float av = A[b*16384 + i*128 + j];
      sm += xv*av; sx += xv;
    }
    CM[(b*64 + d)*128 + j] = sm;
    CXv[(b*64 + d)*128 + j] = sx;
  }
}

#define SJ32 72   // u32 stride for bf16-pair LDS staging
#define SJF  69   // fp32 stride for Yacc staging

// ---- MFMA channel-mix: all 5 groups computed, ONE barrier, all stores at end ----
__global__ __launch_bounds__(256) void k_mix(const u16* __restrict__ Xt, const float* __restrict__ A,
    const float* __restrict__ AAt, const float* __restrict__ rA, const u16* __restrict__ Wb,
    u16* __restrict__ Ua, u16* __restrict__ Ub, u16* __restrict__ Uc, u16* __restrict__ Ud,
    float* __restrict__ Yacc)
{
  const int b = blockIdx.y;
  const int t = threadIdx.x;
  const int wave = t >> 6, lane = t & 63;
  const int col = lane & 15, quad = lane >> 4;
  const int ij0 = blockIdx.x*64;
  const int ij = ij0 + wave*16 + col;

  __shared__ uint32_t lsb[4][32*SJ32];   // bf16-pair staging for Ua..Ud
  __shared__ float lsf[64*SJF];          // fp32 staging for Yacc

  const u16* xp = Xt + ((size_t)(b*16384 + ij))*64 + quad*8;
  short8 xb0 = *(const short8*)xp;
  short8 xb1 = *(const short8*)(xp + 32);

  const float a_s = A[b*16384 + ij];
  const float t_s = AAt[b*16384 + ij];
  const float ri = rA[b*128 + (ij >> 7)];
  const float rj = rA[b*128 + (ij & 127)];

  #pragma unroll
  for (int g = 0; g < 5; g++){
    const int s0_tab[5]  = {0, 2, 4, 5, 6};
    const int nsl_tab[5] = {2, 2, 1, 1, 4};
    const int s0 = s0_tab[g], nsl = nsl_tab[g];

    f32x4 acc[4][4];
    #pragma unroll
    for (int s = 0; s < 4; s++)
      #pragma unroll
      for (int et = 0; et < 4; et++)
        acc[s][et] = (f32x4){0.f,0.f,0.f,0.f};

    #pragma unroll
    for (int s = 0; s < 4; s++){
      if (s >= nsl) break;
      #pragma unroll
      for (int et = 0; et < 4; et++){
        const u16* wp = Wb + ((size_t)((s0 + s)*64 + et*16 + col))*64 + quad*8;
        short8 a0 = *(const short8*)wp;
        short8 a1 = *(const short8*)(wp + 32);
        acc[s][et] = MFMA16(a0, xb0, acc[s][et]);
        acc[s][et] = MFMA16(a1, xb1, acc[s][et]);
      }
    }

    if (g < 4){
      #pragma unroll
      for (int et = 0; et < 4; et++){
        float v[4];
        #pragma unroll
        for (int r = 0; r < 4; r++){
          if (g == 2 || g == 3) v[r] = acc[0][et][r]*a_s;
          else                  v[r] = acc[0][et][r]*a_s + acc[1][et][r];
        }
        uint32_t p0 = (uint32_t)f2b(v[0]) | ((uint32_t)f2b(v[1]) << 16);
        uint32_t p1 = (uint32_t)f2b(v[2]) | ((uint32_t)f2b(v[3]) << 16);
        int ep = et*8 + quad*2;
        lsb[g][ep*SJ32 + wave*16 + col] = p0;
        lsb[g][(ep + 1)*SJ32 + wave*16 + col] = p1;
      }
    } else {
      #pragma unroll
      for (int et = 0; et < 4; et++)
        #pragma unroll
        for (int r = 0; r < 4; r++){
          float v = acc[0][et][r]*t_s + acc[1][et][r]*ri + acc[2][et][r]*rj + acc[3][et][r];
          lsf[(et*16 + quad*4 + r)*SJF + wave*16 + col] = v;
        }
    }
  }
  __syncthreads();   // the ONLY barrier

  const int eo = t >> 2, seg = t & 3;
  const int ep = eo >> 1, sh = (eo & 1)*16;
  #pragma unroll
  for (int g = 0; g < 4; g++){
    const uint32_t* lp = &lsb[g][ep*SJ32 + seg*16];
    short8 v0, v1;
    #pragma unroll
    for (int k = 0; k < 8; k++){
      v0[k] = (short)((lp[k]   >> sh) & 0xffffu);
      v1[k] = (short)((lp[8+k] >> sh) & 0xffffu);
    }
    u16* U = (g==0)?Ua:(g==1)?Ub:(g==2)?Uc:Ud;
    u16* dst = U + ((size_t)(b*64 + eo) << 14) + ij0 + seg*16;
    *(short8*)dst = v0;
    *(short8*)(dst + 8) = v1;
  }
  {
    const float* fp = &lsf[eo*SJF + seg*16];
    float* dst = Yacc + ((size_t)(b*64 + eo) << 14) + ij0 + seg*16;
    #pragma unroll
    for (int q = 0; q < 4; q++)
      *(float4*)(dst + q*4) = make_float4(fp[q*4], fp[q*4+1], fp[q*4+2], fp[q*4+3]);
  }
}

// ---- MFMA: the four A-products, K=512 fused, Yacc += ----
__global__ __launch_bounds__(256) void k_tn(const u16* __restrict__ ATb,
    const u16* __restrict__ UaT, const u16* __restrict__ UbT,
    const u16* __restrict__ Uc, const u16* __restrict__ Ud,
    float* __restrict__ Yacc)
{
  const int blk = blockIdx.x;       // 1024
  const int be = blk >> 2, q = blk & 3;
  const int b = be >> 6;
  const int t = threadIdx.x;
  const int wave = t >> 6, lane = t & 63;
  const int col = lane & 15, quad = lane >> 4;
  const int m0 = (q >> 1)*64 + (wave >> 1)*32;
  const int n0 = (q & 1)*64 + (wave & 1)*32;

  const u16* at  = ATb + (((size_t)b) << 14);
  const u16* uat = UaT + (((size_t)be) << 14);
  const u16* ubt = UbT + (((size_t)be) << 14);
  const u16* uc  = Uc  + (((size_t)be) << 14);
  const u16* ud  = Ud  + (((size_t)be) << 14);
  const u16* sa_t[4] = {uat, at, uc, at};
  const u16* rb_t[4] = {at, ubt, at, ud};

  f32x4 acc[2][2];
  #pragma unroll
  for (int et = 0; et < 2; et++)
    #pragma unroll
    for (int nt = 0; nt < 2; nt++)
      acc[et][nt] = (f32x4){0.f,0.f,0.f,0.f};

  for (int f = 0; f < 4; f++){
    const u16* sa = sa_t[f];
    const u16* rb = rb_t[f];
    #pragma unroll
    for (int kq = 0; kq < 4; kq++){
      int k0 = kq*32 + quad*8;
      short8 a0 = *(const short8*)(sa + (m0 + col)*128 + k0);
      short8 a1 = *(const short8*)(sa + (m0 + 16 + col)*128 + k0);
      short8 b0 = *(const short8*)(rb + (n0 + col)*128 + k0);
      short8 b1 = *(const short8*)(rb + (n0 + 16 + col)*128 + k0);
      acc[0][0] = MFMA16(a0, b0, acc[0][0]);
      acc[0][1] = MFMA16(a0, b1, acc[0][1]);
      acc[1][0] = MFMA16(a1, b0, acc[1][0]);
      acc[1][1] = MFMA16(a1, b1, acc[1][1]);
    }
  }
  #pragma unroll
  for (int et = 0; et < 2; et++)
    #pragma unroll
    for (int nt = 0; nt < 2; nt++)
      #pragma unroll
      for (int r = 0; r < 4; r++){
        int row = m0 + et*16 + quad*4 + r;
        int cc  = n0 + nt*16 + col;
        Yacc[(((size_t)be) << 14) + row*128 + cc] += acc[et][nt][r];
      }
}

// ---- epilogue ----
__global__ __launch_bounds__(256) void k_epi(const float* __restrict__ Yacc, const float* __restrict__ W,
    const float* __restrict__ RM, const float* __restrict__ CM,
    const float* __restrict__ RX, const float* __restrict__ CXv,
    const float* __restrict__ bias, u16* __restrict__ Xout, float* __restrict__ acc4, int last)
{
  const int be = blockIdx.x;
  const int b = be >> 6, e = be & 63;
  __shared__ float radd[128], cadd[128];
  __shared__ float red[4];
  const int t = threadIdx.x;
  if (t < 128){
    int i = t; float s = 0.f;
    for (int d = 0; d < ND; d++){
      int v = (b*ND + d)*NN + i;
      s += W[(640 + d)*64 + e]*RM[v] + W[(704 + d)*64 + e]*CM[v]
         + W[(768 + d)*64 + e]*RX[v] + W[(832 + d)*64 + e]*CXv[v];
    }
    radd[i] = s;
  } else {
    int j = t - 128; float s = 0.f;
    for (int d = 0; d < ND; d++){
      int v = (b*ND + d)*NN + j;
      s += W[(896 + d)*64 + e]*RM[v] + W[(960 + d)*64 + e]*CM[v]
         + W[(1024 + d)*64 + e]*RX[v] + W[(1088 + d)*64 + e]*CXv[v];
    }
    cadd[j] = s;
  }
  __syncthreads();
  const float bv = bias[e];
  const float* Y = Yacc + ((size_t)be << 14);
  if (!last){
    u16* Xo = Xout + ((size_t)be << 14);
    for (int l = 0; l < 64; l++){
      int idx = l*256 + t;
      int ii = idx >> 7, jj = idx & 127;
      float v = Y[idx] + radd[ii] + cadd[jj] + bv;
      v = 1.f/(1.f + __expf(-v));
      Xo[idx] = f2b(v);
    }
  } else {
    float loc = 0.f;
    for (int l = 0; l < 64; l++){
      int idx = l*256 + t;
      int ii = idx >> 7, jj = idx & 127;
      loc += Y[idx] + radd[ii] + cadd[jj] + bv;
    }
    for (int off = 32; off > 0; off >>= 1) loc += __shfl_down(loc, off, 64);
    if ((t & 63) == 0) red[t >> 6] = loc;
    __syncthreads();
    if (t == 0) atomicAdd(&acc4[b], red[0] + red[1] + red[2] + red[3]);
  }
}

__global__ void k_finish(const float* __restrict__ acc4, const int* __restrict__ flag,
                         void* __restrict__ out){
  int b = threadIdx.x;
  if (b >= NB) return;
  float v = acc4[b] * (1.0f/1048576.0f);
  if (*flag) ((float*)out)[b] = v;
  else       ((u16*)out)[b] = f2b(v);
}

extern "C" void kernel_launch(void* const* d_in, const int* in_sizes, int n_in,
                              void* d_out, int out_size, void* d_ws, size_t ws_size,
                              hipStream_t stream)
{
  const void* x   = d_in[0];
  const void* ew  = d_in[1];
  const void* c1  = d_in[2];
  const void* b1  = d_in[3];
  const void* c2  = d_in[4];
  const void* b2  = d_in[5];
  const int* ei  = (const int*)d_in[6];
  const int* bat = (const int*)d_in[7];
  const int E = in_sizes[1];

  char* wsb = (char*)d_ws;
  float* A    = (float*)(wsb + OFF_A);
  float* acc4 = (float*)(wsb + OFF_ACC);
  float* AAt  = (float*)(wsb + OFF_AAT);
  float* rA   = (float*)(wsb + OFF_RA);
  float* W    = (float*)(wsb + OFF_W);
  float* RM   = (float*)(wsb + OFF_RM);
  float* CM   = (float*)(wsb + OFF_CM);
  float* RX   = (float*)(wsb + OFF_RX);
  float* CXv  = (float*)(wsb + OFF_CX);
  int*   flag = (int*)(wsb + OFF_FLAG);
  float* bfv  = (float*)(wsb + OFF_BF);
  u16* ATb = (u16*)(wsb + OFF_ATB);
  u16* Wb  = (u16*)(wsb + OFF_WB);
  u16* X2  = (u16*)(wsb + OFF_X2);
  u16* Xt  = (u16*)(wsb + OFF_XT);
  u16* Ua  = (u16*)(wsb + OFF_UA);
  u16* Ub  = (u16*)(wsb + OFF_UB);
  u16* Uc  = (u16*)(wsb + OFF_UC);
  u16* Ud  = (u16*)(wsb + OFF_UD);
  u16* UaT = (u16*)(wsb + OFF_UAT);
  u16* UbT = (u16*)(wsb + OFF_UBT);
  float* Yacc = (float*)(wsb + OFF_YACC);
  float* xf   = (float*)(wsb + OFF_XF);
  float* ewf  = (float*)(wsb + OFF_EWF);
  float* cf   = (float*)(wsb + OFF_CF);

  hipMemsetAsync(wsb, 0, OFF_AAT, stream);          // zero A + acc4
  hipMemsetAsync(wsb + OFF_FLAG, 0, 256, stream);   // zero flag

  k_detect<<<dim3(1), dim3(256), 0, stream>>>((const u16*)x, flag);
  k_convert<<<dim3(737), dim3(256), 0, stream>>>(x, ew, c1, c2, b1, b2, flag, xf, ewf, cf, bfv);
  k_scatter<<<dim3((E + 255)/256), dim3(256), 0, stream>>>(ei, bat, ewf, A, E);
  k_rA<<<dim3(NB), dim3(128), 0, stream>>>(A, rA);
  k_AAt<<<dim3(8, NB), dim3(256), 0, stream>>>(A, AAt);
  k_at<<<dim3(NB), dim3(256), 0, stream>>>(A, ATb);
  k_makeXt1<<<dim3(NMAT/256), dim3(256), 0, stream>>>(xf, Xt);
  k_buildW<<<dim3(576), dim3(256), 0, stream>>>(cf, W, Wb);

  for (int L = 0; L < 2; L++){
    const float* Wl = W + (size_t)L*1152*64;
    const u16*  Wbl = Wb + (size_t)L*10*64*64;
    if (L == 1)
      k_xt<<<dim3(256, NB), dim3(256), 0, stream>>>(X2, Xt);
    k_rowcol<<<dim3(64, NB), dim3(256), 0, stream>>>(Xt, A, RM, CM, RX, CXv);
    k_mix<<<dim3(256, NB), dim3(256), 0, stream>>>(Xt, A, AAt, rA, Wbl, Ua, Ub, Uc, Ud, Yacc);
    k_ut<<<dim3(256, 2), dim3(256), 0, stream>>>(Ua, Ub, UaT, UbT);
    k_tn<<<dim3(1024), dim3(256), 0, stream>>>(ATb, UaT, UbT, Uc, Ud, Yacc);
    k_epi<<<dim3(256), dim3(256), 0, stream>>>(Yacc, Wl, RM, CM, RX, CXv, bfv + L*64, X2, acc4, L);
  }
  k_finish<<<dim3(1), dim3(64), 0, stream>>>(acc4, flag, d_out);
}

// Round 7
// 339.316 us; speedup vs baseline: 1.0620x; 1.0620x over previous
//
#include <hip/hip_runtime.h>
#include <stdint.h>

typedef unsigned short u16;
using short8 = __attribute__((ext_vector_type(8))) short;
using f32x4  = __attribute__((ext_vector_type(4))) float;

#define NB 4
#define NN 128
#define NF 32
#define ND 64
#define NMAT (NB*ND*NN*NN)   // 4,194,304

// ---- workspace byte offsets (R6 map) ----
#define OFF_A     0u           // fp32 [4][16384]
#define OFF_ACC   262144u      // fp32 [4] (+pad)
#define OFF_AAT   262400u      // fp32 [4][16384]
#define OFF_RA    524544u      // fp32 [4][128]
#define OFF_W     526592u      // fp32 [2][1152][64]
#define OFF_RM    1116416u     // fp32 [4][64][128]
#define OFF_CM    1247488u
#define OFF_RX    1378560u
#define OFF_CX    1509632u
#define OFF_FLAG  1640704u     // int (+pad)
#define OFF_BF    1640960u     // fp32 128 (+pad)
#define OFF_ATB   1641472u     // bf16 [4][128n][128k]  (A^T, k-contig)
#define OFF_WB    1772544u     // bf16 [2][10][64e][64d]
#define OFF_X2    1936384u     // bf16 NMAT (EXCLUSIVE now — no UaT alias)
#define OFF_XT    10324992u    // bf16 [4][16384 ij][64 d]
#define OFF_UA    18713600u    // bf16 NMAT
#define OFF_UB    27102208u
#define OFF_UC    35490816u
#define OFF_UD    43879424u
#define OFF_YACC  52268032u    // fp32 NMAT  (end 69,045,248)
// convert scratch aliased INTO Yacc region (dead before first Yacc write):
#define OFF_XF    (OFF_YACC)            // fp32 16384
#define OFF_EWF   (OFF_YACC + 65536u)   // fp32 8192
#define OFF_CF    (OFF_YACC + 98304u)   // fp32 2*81920
// transpose outputs live in DEAD regions at k_ut2 time:
#define OFF_UAT2  OFF_XT       // Xt dead after k_mix of this layer
#define OFF_UBT2  OFF_UA       // Ua dead after k_ut2's block-local read

__device__ __forceinline__ float b2f(u16 v){
  union { uint32_t u; float f; } x; x.u = ((uint32_t)v) << 16; return x.f;
}
__device__ __forceinline__ u16 f2b(float f){
  union { uint32_t u; float f2; } x; x.f2 = f;
  uint32_t u = x.u;
  return (u16)((u + 0x7FFFu + ((u >> 16) & 1u)) >> 16);
}

#define MFMA16(a,b,c) __builtin_amdgcn_mfma_f32_16x16x32_bf16((a),(b),(c),0,0,0)

__device__ __constant__ signed char dR1[18] = {0,9,1,10,2,3,4,13,14,19,5,7,15,18,6,8,16,17};
__device__ __constant__ signed char dR2[18] = {-1,11,-1,12,-1,-1,-1,-1,-1,-1,-1,-1,-1,-1,-1,-1,-1,-1};

// ---- dtype detect ----
__global__ void k_detect(const u16* __restrict__ x16, int* __restrict__ flag){
  int t = threadIdx.x;
  int hit = 0;
  for (int k = t; k < 16384; k += 256){
    u16 u = x16[k];
    int e = (u >> 7) & 0xFF;
    if (e >= 0x90) hit = 1;
  }
  if (hit) atomicOr(flag, 1);
}

__global__ void k_convert(const void* __restrict__ xs, const void* __restrict__ ews,
                          const void* __restrict__ c1s, const void* __restrict__ c2s,
                          const void* __restrict__ b1s, const void* __restrict__ b2s,
                          const int* __restrict__ flag,
                          float* __restrict__ xf, float* __restrict__ ewf,
                          float* __restrict__ cf, float* __restrict__ bfv){
  int t = blockIdx.x*256 + threadIdx.x;
  if (t >= 188544) return;
  int isf = *flag;
  const void* src; int idx; float* dst;
  if (t < 16384)      { src = xs;  idx = t;          dst = xf + idx; }
  else if (t < 24576) { src = ews; idx = t - 16384;  dst = ewf + idx; }
  else if (t < 106496){ src = c1s; idx = t - 24576;  dst = cf + idx; }
  else if (t < 188416){ src = c2s; idx = t - 106496; dst = cf + 81920 + idx; }
  else if (t < 188480){ src = b1s; idx = t - 188416; dst = bfv + idx; }
  else                { src = b2s; idx = t - 188480; dst = bfv + 64 + idx; }
  float v = isf ? ((const float*)src)[idx] : b2f(((const u16*)src)[idx]);
  *dst = v;
}

__global__ void k_scatter(const int* __restrict__ ei, const int* __restrict__ bat,
                          const float* __restrict__ ew, float* __restrict__ A, int E){
  int t = blockIdx.x*256 + threadIdx.x;
  if (t >= E) return;
  int s = ei[t], dnode = ei[E + t];
  int g = bat[s];
  int r = s - g*NN, c = dnode - g*NN;
  atomicAdd(&A[(g*NN + r)*NN + c], ew[t]);
}

__global__ void k_rA(const float* __restrict__ A, float* __restrict__ rA){
  int b = blockIdx.x, i = threadIdx.x;
  const float* Ab = A + (b*NN + i)*NN;
  float s = 0.f;
  for (int j = 0; j < NN; j++) s += Ab[j];
  rA[b*NN + i] = s;
}

__global__ __launch_bounds__(256) void k_AAt(const float* __restrict__ A, float* __restrict__ AAt){
  int b = blockIdx.y, iq = blockIdx.x;
  int t = threadIdx.x;
  int j = t & 127, ih = t >> 7;
  const float* Ab = A + b*NN*NN;
  float acc[8] = {0,0,0,0,0,0,0,0};
  for (int k = 0; k < NN; k++){
    float aj = Ab[j*NN + k];
    #pragma unroll
    for (int ii = 0; ii < 8; ii++){
      int i = iq*16 + ih*8 + ii;
      acc[ii] += Ab[i*NN + k] * aj;
    }
  }
  #pragma unroll
  for (int ii = 0; ii < 8; ii++){
    int i = iq*16 + ih*8 + ii;
    AAt[(b*NN + i)*NN + j] = acc[ii];
  }
}

// ---- ATb[b][n][k] = bf16(A[b][k][n]) ----
__global__ __launch_bounds__(256) void k_at(const float* __restrict__ A, u16* __restrict__ ATb){
  int b = blockIdx.x;
  __shared__ float lds[128][129];
  int t = threadIdx.x;
  for (int l = 0; l < 64; l++){
    int idx = l*256 + t;
    lds[idx >> 7][idx & 127] = A[b*16384 + idx];
  }
  __syncthreads();
  for (int l = 0; l < 64; l++){
    int idx = l*256 + t;
    int r = idx >> 7, c = idx & 127;
    ATb[b*16384 + idx] = f2b(lds[c][r]);
  }
}

// ---- layer-1 Xt[b][ij][d] directly from x ----
__global__ void k_makeXt1(const float* __restrict__ xf, u16* __restrict__ Xt){
  int idx = blockIdx.x*256 + threadIdx.x;
  if (idx >= NMAT) return;
  int d = idx & 63, ij = (idx >> 6) & 16383, b = idx >> 20;
  int i = ij >> 7, j = ij & 127;
  float v = (d < NF) ? xf[(b*NN + i)*NF + d] : xf[(b*NN + j)*NF + (d - NF)];
  Xt[idx] = f2b(v);
}

// ---- X[b][e][ij] -> Xt[b][ij][e] via LDS tiles ----
__global__ __launch_bounds__(256) void k_xt(const u16* __restrict__ X, u16* __restrict__ Xt){
  int b = blockIdx.y;
  int ij0 = blockIdx.x*64;
  __shared__ u16 lds[64][65];
  int t = threadIdx.x;
  #pragma unroll
  for (int l = 0; l < 2; l++){
    int idx = l*2048 + t*8;
    int d = idx >> 6, c = idx & 63;
    const u16* p = X + ((size_t)(b*64 + d))*16384 + ij0 + c;
    short8 v = *(const short8*)p;
    #pragma unroll
    for (int k = 0; k < 8; k++) lds[d][c + k] = (u16)v[k];
  }
  __syncthreads();
  #pragma unroll
  for (int l = 0; l < 2; l++){
    int idx = l*2048 + t*8;
    int r = idx >> 6, c = idx & 63;
    short8 v;
    #pragma unroll
    for (int k = 0; k < 8; k++) v[k] = (short)lds[c + k][r];
    *(short8*)(Xt + ((size_t)(b*16384 + ij0 + r))*64 + c) = v;
  }
}

// ---- both transposes in one block: Ua->UaT(Xt region), Ub->UbT(Ua region) ----
// Block be reads Ua[be] fully into LDS before anything overwrites Ua[be]; slabs block-disjoint.
__global__ __launch_bounds__(256) void k_ut2(const u16* __restrict__ Ua, const u16* __restrict__ Ub,
                                             u16* __restrict__ UaT, u16* __restrict__ UbT){
  int be = blockIdx.x;
  __shared__ u16 lds[128][129];
  int t = threadIdx.x;
  for (int h = 0; h < 2; h++){
    const u16* src = (h ? Ub : Ua) + ((size_t)be << 14);
    u16* dst = (h ? UbT : UaT) + ((size_t)be << 14);
    if (h) __syncthreads();           // prior lds reads complete before refill
    #pragma unroll
    for (int l = 0; l < 8; l++){
      int idx = l*2048 + t*8;
      int r = idx >> 7, c = idx & 127;
      short8 v = *(const short8*)(src + r*128 + c);
      #pragma unroll
      for (int k = 0; k < 8; k++) lds[r][c + k] = (u16)v[k];
    }
    __syncthreads();
    #pragma unroll
    for (int l = 0; l < 8; l++){
      int idx = l*2048 + t*8;
      int r = idx >> 7, c = idx & 127;
      short8 v;
      #pragma unroll
      for (int k = 0; k < 8; k++) v[k] = (short)lds[c + k][r];
      *(short8*)(dst + r*128 + c) = v;
    }
  }
}

// ---- W fp32 + bf16 Wb[L][slot<10][e][d] ----
__global__ void k_buildW(const float* __restrict__ cf, float* __restrict__ W, u16* __restrict__ Wb){
  int gl = blockIdx.x*256 + threadIdx.x;
  if (gl >= 2*1152*64) return;
  int L = gl / (1152*64);
  int rem = gl - L*1152*64;
  int row = rem >> 6, e = rem & 63;
  int slot = row >> 6, d = row & 63;
  const float* cc = cf + L*81920;
  int base = (d*64 + e)*20;
  float v = cc[base + dR1[slot]];
  if (dR2[slot] >= 0) v += cc[base + dR2[slot]];
  float scale = (slot == 9) ? 1.0f : (1.0f/128.0f);
  v *= scale;
  W[gl] = v;
  if (slot < 10)
    Wb[(((size_t)L*10 + slot)*64 + e)*64 + d] = f2b(v);
}

// ---- row/col sums of M=X*A and X ----
__global__ __launch_bounds__(256) void k_rowcol(const u16* __restrict__ Xt, const float* __restrict__ A,
                         float* __restrict__ RM, float* __restrict__ CM,
                         float* __restrict__ RX, float* __restrict__ CXv){
  int b = blockIdx.y;
  int t = threadIdx.x;
  int d = t & 63;
  int task = blockIdx.x*4 + (t >> 6);
  float sm = 0.f, sx = 0.f;
  if (task < 128){
    int i = task;
    for (int j = 0; j < 128; j++){
      float xv = b2f(Xt[((size_t)(b*16384 + i*128 + j))*64 + d]);
      float av = A[b*16384 + i*128 + j];
      sm += xv*av; sx += xv;
    }
    RM[(b*64 + d)*128 + i] = sm;
    RX[(b*64 + d)*128 + i] = sx;
  } else {
    int j = task - 128;
    for (int i = 0; i < 128; i++){
      float xv = b2f(Xt[((size_t)(b*16384 + i*128 + j))*64 + d]);
      float av = A[b*16384 + i*128 + j];
      sm += xv*av; sx += xv;
    }
    CM[(b*64 + d)*128 + j] = sm;
    CXv[(b*64 + d)*128 + j] = sx;
  }
}

#define SJ32 72   // u32 stride for bf16-pair LDS staging
#define SJF  69   // fp32 stride for Yacc staging

// ---- MFMA channel-mix (R6 verbatim): one barrier, all stores at end ----
__global__ __launch_bounds__(256) void k_mix(const u16* __restrict__ Xt, const float* __restrict__ A,
    const float* __restrict__ AAt, const float* __restrict__ rA, const u16* __restrict__ Wb,
    u16* __restrict__ Ua, u16* __restrict__ Ub, u16* __restrict__ Uc, u16* __restrict__ Ud,
    float* __restrict__ Yacc)
{
  const int b = blockIdx.y;
  const int t = threadIdx.x;
  const int wave = t >> 6, lane = t & 63;
  const int col = lane & 15, quad = lane >> 4;
  const int ij0 = blockIdx.x*64;
  const int ij = ij0 + wave*16 + col;

  __shared__ uint32_t lsb[4][32*SJ32];
  __shared__ float lsf[64*SJF];

  const u16* xp = Xt + ((size_t)(b*16384 + ij))*64 + quad*8;
  short8 xb0 = *(const short8*)xp;
  short8 xb1 = *(const short8*)(xp + 32);

  const float a_s = A[b*16384 + ij];
  const float t_s = AAt[b*16384 + ij];
  const float ri = rA[b*128 + (ij >> 7)];
  const float rj = rA[b*128 + (ij & 127)];

  #pragma unroll
  for (int g = 0; g < 5; g++){
    const int s0_tab[5]  = {0, 2, 4, 5, 6};
    const int nsl_tab[5] = {2, 2, 1, 1, 4};
    const int s0 = s0_tab[g], nsl = nsl_tab[g];

    f32x4 acc[4][4];
    #pragma unroll
    for (int s = 0; s < 4; s++)
      #pragma unroll
      for (int et = 0; et < 4; et++)
        acc[s][et] = (f32x4){0.f,0.f,0.f,0.f};

    #pragma unroll
    for (int s = 0; s < 4; s++){
      if (s >= nsl) break;
      #pragma unroll
      for (int et = 0; et < 4; et++){
        const u16* wp = Wb + ((size_t)((s0 + s)*64 + et*16 + col))*64 + quad*8;
        short8 a0 = *(const short8*)wp;
        short8 a1 = *(const short8*)(wp + 32);
        acc[s][et] = MFMA16(a0, xb0, acc[s][et]);
        acc[s][et] = MFMA16(a1, xb1, acc[s][et]);
      }
    }

    if (g < 4){
      #pragma unroll
      for (int et = 0; et < 4; et++){
        float v[4];
        #pragma unroll
        for (int r = 0; r < 4; r++){
          if (g == 2 || g == 3) v[r] = acc[0][et][r]*a_s;
          else                  v[r] = acc[0][et][r]*a_s + acc[1][et][r];
        }
        uint32_t p0 = (uint32_t)f2b(v[0]) | ((uint32_t)f2b(v[1]) << 16);
        uint32_t p1 = (uint32_t)f2b(v[2]) | ((uint32_t)f2b(v[3]) << 16);
        int ep = et*8 + quad*2;
        lsb[g][ep*SJ32 + wave*16 + col] = p0;
        lsb[g][(ep + 1)*SJ32 + wave*16 + col] = p1;
      }
    } else {
      #pragma unroll
      for (int et = 0; et < 4; et++)
        #pragma unroll
        for (int r = 0; r < 4; r++){
          float v = acc[0][et][r]*t_s + acc[1][et][r]*ri + acc[2][et][r]*rj + acc[3][et][r];
          lsf[(et*16 + quad*4 + r)*SJF + wave*16 + col] = v;
        }
    }
  }
  __syncthreads();

  const int eo = t >> 2, seg = t & 3;
  const int ep = eo >> 1, sh = (eo & 1)*16;
  #pragma unroll
  for (int g = 0; g < 4; g++){
    const uint32_t* lp = &lsb[g][ep*SJ32 + seg*16];
    short8 v0, v1;
    #pragma unroll
    for (int k = 0; k < 8; k++){
      v0[k] = (short)((lp[k]   >> sh) & 0xffffu);
      v1[k] = (short)((lp[8+k] >> sh) & 0xffffu);
    }
    u16* U = (g==0)?Ua:(g==1)?Ub:(g==2)?Uc:Ud;
    u16* dst = U + ((size_t)(b*64 + eo) << 14) + ij0 + seg*16;
    *(short8*)dst = v0;
    *(short8*)(dst + 8) = v1;
  }
  {
    const float* fp = &lsf[eo*SJF + seg*16];
    float* dst = Yacc + ((size_t)(b*64 + eo) << 14) + ij0 + seg*16;
    #pragma unroll
    for (int q = 0; q < 4; q++)
      *(float4*)(dst + q*4) = make_float4(fp[q*4], fp[q*4+1], fp[q*4+2], fp[q*4+3]);
  }
}

// ---- fused: four A-products (MFMA) + Yacc + broadcast + bias + sigmoid/reduce ----
__global__ __launch_bounds__(256) void k_tne(const u16* __restrict__ ATb,
    const u16* __restrict__ UaT, const u16* __restrict__ UbT,
    const u16* __restrict__ Uc, const u16* __restrict__ Ud,
    const float* __restrict__ Yacc, const float* __restrict__ W,
    const float* __restrict__ RM, const float* __restrict__ CM,
    const float* __restrict__ RX, const float* __restrict__ CXv,
    const float* __restrict__ bias, u16* __restrict__ Xout, float* __restrict__ acc4, int last)
{
  const int nh = blockIdx.x, be = blockIdx.y;
  const int b = be >> 6, e = be & 63;
  const int t = threadIdx.x, wave = t >> 6, lane = t & 63;
  const int col = lane & 15, quad = lane >> 4;
  const int m0 = (wave >> 1)*64;
  const int n0 = nh*64 + (wave & 1)*32;

  __shared__ float radd[128], cadd[128];
  __shared__ uint32_t stg[64*68];
  __shared__ float red[4];

  if (t < 128){
    int i = t; float s = 0.f;
    for (int d = 0; d < ND; d++){
      int v = (b*ND + d)*NN + i;
      s += W[(640 + d)*64 + e]*RM[v] + W[(704 + d)*64 + e]*CM[v]
         + W[(768 + d)*64 + e]*RX[v] + W[(832 + d)*64 + e]*CXv[v];
    }
    radd[i] = s;
  } else {
    int j = t - 128; float s = 0.f;
    for (int d = 0; d < ND; d++){
      int v = (b*ND + d)*NN + j;
      s += W[(896 + d)*64 + e]*RM[v] + W[(960 + d)*64 + e]*CM[v]
         + W[(1024 + d)*64 + e]*RX[v] + W[(1088 + d)*64 + e]*CXv[v];
    }
    cadd[j] = s;
  }

  f32x4 acc[4][2];
  #pragma unroll
  for (int mt = 0; mt < 4; mt++)
    #pragma unroll
    for (int nt = 0; nt < 2; nt++)
      acc[mt][nt] = (f32x4){0.f,0.f,0.f,0.f};

  const u16* at = ATb + ((size_t)b << 14);
  const u16* sa_t[4] = {UaT + ((size_t)be << 14), at, Uc + ((size_t)be << 14), at};
  const u16* rb_t[4] = {at, UbT + ((size_t)be << 14), at, Ud + ((size_t)be << 14)};

  #pragma unroll
  for (int f = 0; f < 4; f++){
    const u16* sa = sa_t[f];
    const u16* rb = rb_t[f];
    #pragma unroll
    for (int kq = 0; kq < 4; kq++){
      int k0 = kq*32 + quad*8;
      short8 bf0 = *(const short8*)(rb + (n0 + col)*128 + k0);
      short8 bf1 = *(const short8*)(rb + (n0 + 16 + col)*128 + k0);
      #pragma unroll
      for (int mt = 0; mt < 4; mt++){
        short8 af = *(const short8*)(sa + (m0 + mt*16 + col)*128 + k0);
        acc[mt][0] = MFMA16(af, bf0, acc[mt][0]);
        acc[mt][1] = MFMA16(af, bf1, acc[mt][1]);
      }
    }
  }
  __syncthreads();   // radd/cadd ready

  const float bv = bias[e];
  const float* Y = Yacc + ((size_t)be << 14);
  if (!last){
    #pragma unroll
    for (int mt = 0; mt < 4; mt++)
      #pragma unroll
      for (int nt = 0; nt < 2; nt++)
        #pragma unroll
        for (int rp = 0; rp < 2; rp++){
          uint32_t p = 0;
          #pragma unroll
          for (int h = 0; h < 2; h++){
            int r = rp*2 + h;
            int row = m0 + mt*16 + quad*4 + r;
            int cn = n0 + nt*16 + col;
            float v = acc[mt][nt][r] + Y[row*128 + cn] + radd[row] + cadd[cn] + bv;
            v = 1.f/(1.f + __expf(-v));
            p |= ((uint32_t)f2b(v)) << (16*h);
          }
          int ipair = (m0 + mt*16 + quad*4) >> 1;
          stg[(ipair + rp)*68 + (wave & 1)*32 + nt*16 + col] = p;
        }
    __syncthreads();
    const uint32_t* lp = &stg[(t >> 2)*68 + (t & 1)*32];
    const int sh = ((t >> 1) & 1)*16;
    u16* dst = Xout + ((size_t)be << 14) + (size_t)(t >> 1)*128 + nh*64 + (t & 1)*32;
    #pragma unroll
    for (int q2 = 0; q2 < 4; q2++){
      short8 v;
      #pragma unroll
      for (int k = 0; k < 8; k++) v[k] = (short)((lp[q2*8 + k] >> sh) & 0xffffu);
      *(short8*)(dst + q2*8) = v;
    }
  } else {
    float loc = 0.f;
    #pragma unroll
    for (int mt = 0; mt < 4; mt++)
      #pragma unroll
      for (int nt = 0; nt < 2; nt++)
        #pragma unroll
        for (int r = 0; r < 4; r++){
          int row = m0 + mt*16 + quad*4 + r;
          int cn = n0 + nt*16 + col;
          loc += acc[mt][nt][r] + Y[row*128 + cn] + radd[row] + cadd[cn] + bv;
        }
    for (int off = 32; off > 0; off >>= 1) loc += __shfl_down(loc, off, 64);
    if (lane == 0) red[wave] = loc;
    __syncthreads();
    if (t == 0) atomicAdd(&acc4[b], red[0] + red[1] + red[2] + red[3]);
  }
}

__global__ void k_finish(const float* __restrict__ acc4, const int* __restrict__ flag,
                         void* __restrict__ out){
  int b = threadIdx.x;
  if (b >= NB) return;
  float v = acc4[b] * (1.0f/1048576.0f);
  if (*flag) ((float*)out)[b] = v;
  else       ((u16*)out)[b] = f2b(v);
}

extern "C" void kernel_launch(void* const* d_in, const int* in_sizes, int n_in,
                              void* d_out, int out_size, void* d_ws, size_t ws_size,
                              hipStream_t stream)
{
  const void* x   = d_in[0];
  const void* ew  = d_in[1];
  const void* c1  = d_in[2];
  const void* b1  = d_in[3];
  const void* c2  = d_in[4];
  const void* b2  = d_in[5];
  const int* ei  = (const int*)d_in[6];
  const int* bat = (const int*)d_in[7];
  const int E = in_sizes[1];

  char* wsb = (char*)d_ws;
  float* A    = (float*)(wsb + OFF_A);
  float* acc4 = (float*)(wsb + OFF_ACC);
  float* AAt  = (float*)(wsb + OFF_AAT);
  float* rA   = (float*)(wsb + OFF_RA);
  float* W    = (float*)(wsb + OFF_W);
  float* RM   = (float*)(wsb + OFF_RM);
  float* CM   = (float*)(wsb + OFF_CM);
  float* RX   = (float*)(wsb + OFF_RX);
  float* CXv  = (float*)(wsb + OFF_CX);
  int*   flag = (int*)(wsb + OFF_FLAG);
  float* bfv  = (float*)(wsb + OFF_BF);
  u16* ATb = (u16*)(wsb + OFF_ATB);
  u16* Wb  = (u16*)(wsb + OFF_WB);
  u16* X2  = (u16*)(wsb + OFF_X2);
  u16* Xt  = (u16*)(wsb + OFF_XT);
  u16* Ua  = (u16*)(wsb + OFF_UA);
  u16* Ub  = (u16*)(wsb + OFF_UB);
  u16* Uc  = (u16*)(wsb + OFF_UC);
  u16* Ud  = (u16*)(wsb + OFF_UD);
  u16* UaT = (u16*)(wsb + OFF_UAT2);   // = Xt region
  u16* UbT = (u16*)(wsb + OFF_UBT2);   // = Ua region
  float* Yacc = (float*)(wsb + OFF_YACC);
  float* xf   = (float*)(wsb + OFF_XF);
  float* ewf  = (float*)(wsb + OFF_EWF);
  float* cf   = (float*)(wsb + OFF_CF);

  hipMemsetAsync(wsb, 0, OFF_AAT, stream);          // zero A + acc4
  hipMemsetAsync(wsb + OFF_FLAG, 0, 256, stream);   // zero flag

  k_detect<<<dim3(1), dim3(256), 0, stream>>>((const u16*)x, flag);
  k_convert<<<dim3(737), dim3(256), 0, stream>>>(x, ew, c1, c2, b1, b2, flag, xf, ewf, cf, bfv);
  k_scatter<<<dim3((E + 255)/256), dim3(256), 0, stream>>>(ei, bat, ewf, A, E);
  k_rA<<<dim3(NB), dim3(128), 0, stream>>>(A, rA);
  k_AAt<<<dim3(8, NB), dim3(256), 0, stream>>>(A, AAt);
  k_at<<<dim3(NB), dim3(256), 0, stream>>>(A, ATb);
  k_makeXt1<<<dim3(NMAT/256), dim3(256), 0, stream>>>(xf, Xt);
  k_buildW<<<dim3(576), dim3(256), 0, stream>>>(cf, W, Wb);

  for (int L = 0; L < 2; L++){
    const float* Wl = W + (size_t)L*1152*64;
    const u16*  Wbl = Wb + (size_t)L*10*64*64;
    if (L == 1)
      k_xt<<<dim3(256, NB), dim3(256), 0, stream>>>(X2, Xt);
    k_rowcol<<<dim3(64, NB), dim3(256), 0, stream>>>(Xt, A, RM, CM, RX, CXv);
    k_mix<<<dim3(256, NB), dim3(256), 0, stream>>>(Xt, A, AAt, rA, Wbl, Ua, Ub, Uc, Ud, Yacc);
    k_ut2<<<dim3(256), dim3(256), 0, stream>>>(Ua, Ub, UaT, UbT);
    k_tne<<<dim3(2, 256), dim3(256), 0, stream>>>(ATb, UaT, UbT, Uc, Ud, Yacc, Wl,
                                                  RM, CM, RX, CXv, bfv + L*64, X2, acc4, L);
  }
  k_finish<<<dim3(1), dim3(64), 0, stream>>>(acc4, flag, d_out);
}

// Round 8
// 290.991 us; speedup vs baseline: 1.2383x; 1.1661x over previous
//
#include <hip/hip_runtime.h>
#include <stdint.h>

typedef unsigned short u16;
using short8 = __attribute__((ext_vector_type(8))) short;
using f32x4  = __attribute__((ext_vector_type(4))) float;

#define NB 4
#define NN 128
#define NF 32
#define ND 64
#define NMAT (NB*ND*NN*NN)   // 4,194,304

// ---- workspace byte offsets (R7 map) ----
#define OFF_A     0u
#define OFF_ACC   262144u
#define OFF_AAT   262400u
#define OFF_RA    524544u
#define OFF_W     526592u
#define OFF_RM    1116416u
#define OFF_CM    1247488u
#define OFF_RX    1378560u
#define OFF_CX    1509632u
#define OFF_FLAG  1640704u
#define OFF_BF    1640960u
#define OFF_ATB   1641472u
#define OFF_WB    1772544u
#define OFF_X2    1936384u
#define OFF_XT    10324992u
#define OFF_UA    18713600u
#define OFF_UB    27102208u
#define OFF_UC    35490816u
#define OFF_UD    43879424u
#define OFF_YACC  52268032u
#define OFF_XF    (OFF_YACC)
#define OFF_EWF   (OFF_YACC + 65536u)
#define OFF_CF    (OFF_YACC + 98304u)
#define OFF_UAT2  OFF_XT
#define OFF_UBT2  OFF_UA

__device__ __forceinline__ float b2f(u16 v){
  union { uint32_t u; float f; } x; x.u = ((uint32_t)v) << 16; return x.f;
}
__device__ __forceinline__ u16 f2b(float f){
  union { uint32_t u; float f2; } x; x.f2 = f;
  uint32_t u = x.u;
  return (u16)((u + 0x7FFFu + ((u >> 16) & 1u)) >> 16);
}

#define MFMA16(a,b,c) __builtin_amdgcn_mfma_f32_16x16x32_bf16((a),(b),(c),0,0,0)

__device__ __constant__ signed char dR1[18] = {0,9,1,10,2,3,4,13,14,19,5,7,15,18,6,8,16,17};
__device__ __constant__ signed char dR2[18] = {-1,11,-1,12,-1,-1,-1,-1,-1,-1,-1,-1,-1,-1,-1,-1,-1,-1};

// ---- dtype detect ----
__global__ void k_detect(const u16* __restrict__ x16, int* __restrict__ flag){
  int t = threadIdx.x;
  int hit = 0;
  for (int k = t; k < 16384; k += 256){
    u16 u = x16[k];
    int e = (u >> 7) & 0xFF;
    if (e >= 0x90) hit = 1;
  }
  if (hit) atomicOr(flag, 1);
}

__global__ void k_convert(const void* __restrict__ xs, const void* __restrict__ ews,
                          const void* __restrict__ c1s, const void* __restrict__ c2s,
                          const void* __restrict__ b1s, const void* __restrict__ b2s,
                          const int* __restrict__ flag,
                          float* __restrict__ xf, float* __restrict__ ewf,
                          float* __restrict__ cf, float* __restrict__ bfv){
  int t = blockIdx.x*256 + threadIdx.x;
  if (t >= 188544) return;
  int isf = *flag;
  const void* src; int idx; float* dst;
  if (t < 16384)      { src = xs;  idx = t;          dst = xf + idx; }
  else if (t < 24576) { src = ews; idx = t - 16384;  dst = ewf + idx; }
  else if (t < 106496){ src = c1s; idx = t - 24576;  dst = cf + idx; }
  else if (t < 188416){ src = c2s; idx = t - 106496; dst = cf + 81920 + idx; }
  else if (t < 188480){ src = b1s; idx = t - 188416; dst = bfv + idx; }
  else                { src = b2s; idx = t - 188480; dst = bfv + 64 + idx; }
  float v = isf ? ((const float*)src)[idx] : b2f(((const u16*)src)[idx]);
  *dst = v;
}

__global__ void k_scatter(const int* __restrict__ ei, const int* __restrict__ bat,
                          const float* __restrict__ ew, float* __restrict__ A, int E){
  int t = blockIdx.x*256 + threadIdx.x;
  if (t >= E) return;
  int s = ei[t], dnode = ei[E + t];
  int g = bat[s];
  int r = s - g*NN, c = dnode - g*NN;
  atomicAdd(&A[(g*NN + r)*NN + c], ew[t]);
}

__global__ void k_rA(const float* __restrict__ A, float* __restrict__ rA){
  int b = blockIdx.x, i = threadIdx.x;
  const float* Ab = A + (b*NN + i)*NN;
  float s = 0.f;
  for (int j = 0; j < NN; j++) s += Ab[j];
  rA[b*NN + i] = s;
}

__global__ __launch_bounds__(256) void k_AAt(const float* __restrict__ A, float* __restrict__ AAt){
  int b = blockIdx.y, iq = blockIdx.x;
  int t = threadIdx.x;
  int j = t & 127, ih = t >> 7;
  const float* Ab = A + b*NN*NN;
  float acc[8] = {0,0,0,0,0,0,0,0};
  for (int k = 0; k < NN; k++){
    float aj = Ab[j*NN + k];
    #pragma unroll
    for (int ii = 0; ii < 8; ii++){
      int i = iq*16 + ih*8 + ii;
      acc[ii] += Ab[i*NN + k] * aj;
    }
  }
  #pragma unroll
  for (int ii = 0; ii < 8; ii++){
    int i = iq*16 + ih*8 + ii;
    AAt[(b*NN + i)*NN + j] = acc[ii];
  }
}

// ---- ATb[b][n][k] = bf16(A[b][k][n]) ----
__global__ __launch_bounds__(256) void k_at(const float* __restrict__ A, u16* __restrict__ ATb){
  int b = blockIdx.x;
  __shared__ float lds[128][129];
  int t = threadIdx.x;
  for (int l = 0; l < 64; l++){
    int idx = l*256 + t;
    lds[idx >> 7][idx & 127] = A[b*16384 + idx];
  }
  __syncthreads();
  for (int l = 0; l < 64; l++){
    int idx = l*256 + t;
    int r = idx >> 7, c = idx & 127;
    ATb[b*16384 + idx] = f2b(lds[c][r]);
  }
}

// ---- layer-1 Xt[b][ij][d] from xf, 8-wide vectorized ----
__global__ void k_makeXt1(const float* __restrict__ xf, u16* __restrict__ Xt){
  int gid = blockIdx.x*256 + threadIdx.x;      // 524288 threads
  if (gid >= NMAT/8) return;
  int d0 = (gid & 7)*8;
  int ij = (gid >> 3) & 16383;
  int b  = gid >> 17;
  int i = ij >> 7, j = ij & 127;
  const float* src = (d0 < NF) ? &xf[(b*NN + i)*NF + d0] : &xf[(b*NN + j)*NF + (d0 - NF)];
  float4 f0 = *(const float4*)src;
  float4 f1 = *(const float4*)(src + 4);
  short8 v;
  v[0]=(short)f2b(f0.x); v[1]=(short)f2b(f0.y); v[2]=(short)f2b(f0.z); v[3]=(short)f2b(f0.w);
  v[4]=(short)f2b(f1.x); v[5]=(short)f2b(f1.y); v[6]=(short)f2b(f1.z); v[7]=(short)f2b(f1.w);
  *(short8*)(Xt + ((size_t)(b*16384 + ij))*64 + d0) = v;
}

// ---- X[b][e][ij] -> Xt[b][ij][e] via LDS tiles ----
__global__ __launch_bounds__(256) void k_xt(const u16* __restrict__ X, u16* __restrict__ Xt){
  int b = blockIdx.y;
  int ij0 = blockIdx.x*64;
  __shared__ u16 lds[64][65];
  int t = threadIdx.x;
  #pragma unroll
  for (int l = 0; l < 2; l++){
    int idx = l*2048 + t*8;
    int d = idx >> 6, c = idx & 63;
    const u16* p = X + ((size_t)(b*64 + d))*16384 + ij0 + c;
    short8 v = *(const short8*)p;
    #pragma unroll
    for (int k = 0; k < 8; k++) lds[d][c + k] = (u16)v[k];
  }
  __syncthreads();
  #pragma unroll
  for (int l = 0; l < 2; l++){
    int idx = l*2048 + t*8;
    int r = idx >> 6, c = idx & 63;
    short8 v;
    #pragma unroll
    for (int k = 0; k < 8; k++) v[k] = (short)lds[c + k][r];
    *(short8*)(Xt + ((size_t)(b*16384 + ij0 + r))*64 + c) = v;
  }
}

// ---- both transposes in one block: Ua->UaT(Xt region), Ub->UbT(Ua region) ----
__global__ __launch_bounds__(256) void k_ut2(const u16* __restrict__ Ua, const u16* __restrict__ Ub,
                                             u16* __restrict__ UaT, u16* __restrict__ UbT){
  int be = blockIdx.x;
  __shared__ u16 lds[128][129];
  int t = threadIdx.x;
  for (int h = 0; h < 2; h++){
    const u16* src = (h ? Ub : Ua) + ((size_t)be << 14);
    u16* dst = (h ? UbT : UaT) + ((size_t)be << 14);
    if (h) __syncthreads();
    #pragma unroll
    for (int l = 0; l < 8; l++){
      int idx = l*2048 + t*8;
      int r = idx >> 7, c = idx & 127;
      short8 v = *(const short8*)(src + r*128 + c);
      #pragma unroll
      for (int k = 0; k < 8; k++) lds[r][c + k] = (u16)v[k];
    }
    __syncthreads();
    #pragma unroll
    for (int l = 0; l < 8; l++){
      int idx = l*2048 + t*8;
      int r = idx >> 7, c = idx & 127;
      short8 v;
      #pragma unroll
      for (int k = 0; k < 8; k++) v[k] = (short)lds[c + k][r];
      *(short8*)(dst + r*128 + c) = v;
    }
  }
}

// ---- W fp32 + bf16 Wb[L][slot<10][e][d] ----
__global__ void k_buildW(const float* __restrict__ cf, float* __restrict__ W, u16* __restrict__ Wb){
  int gl = blockIdx.x*256 + threadIdx.x;
  if (gl >= 2*1152*64) return;
  int L = gl / (1152*64);
  int rem = gl - L*1152*64;
  int row = rem >> 6, e = rem & 63;
  int slot = row >> 6, d = row & 63;
  const float* cc = cf + L*81920;
  int base = (d*64 + e)*20;
  float v = cc[base + dR1[slot]];
  if (dR2[slot] >= 0) v += cc[base + dR2[slot]];
  float scale = (slot == 9) ? 1.0f : (1.0f/128.0f);
  v *= scale;
  W[gl] = v;
  if (slot < 10)
    Wb[(((size_t)L*10 + slot)*64 + e)*64 + d] = f2b(v);
}

// ---- row/col sums of M=X*A and X ----
__global__ __launch_bounds__(256) void k_rowcol(const u16* __restrict__ Xt, const float* __restrict__ A,
                         float* __restrict__ RM, float* __restrict__ CM,
                         float* __restrict__ RX, float* __restrict__ CXv){
  int b = blockIdx.y;
  int t = threadIdx.x;
  int d = t & 63;
  int task = blockIdx.x*4 + (t >> 6);
  float sm = 0.f, sx = 0.f;
  if (task < 128){
    int i = task;
    for (int j = 0; j < 128; j++){
      float xv = b2f(Xt[((size_t)(b*16384 + i*128 + j))*64 + d]);
      float av = A[b*16384 + i*128 + j];
      sm += xv*av; sx += xv;
    }
    RM[(b*64 + d)*128 + i] = sm;
    RX[(b*64 + d)*128 + i] = sx;
  } else {
    int j = task - 128;
    for (int i = 0; i < 128; i++){
      float xv = b2f(Xt[((size_t)(b*16384 + i*128 + j))*64 + d]);
      float av = A[b*16384 + i*128 + j];
      sm += xv*av; sx += xv;
    }
    CM[(b*64 + d)*128 + j] = sm;
    CXv[(b*64 + d)*128 + j] = sx;
  }
}

#define SJ32 72
#define SJF  69

// ---- MFMA channel-mix: et-per-wave, ALL loads hoisted to registers, one barrier ----
__global__ __launch_bounds__(256) void k_mix(const u16* __restrict__ Xt, const float* __restrict__ A,
    const float* __restrict__ AAt, const float* __restrict__ rA, const u16* __restrict__ Wb,
    u16* __restrict__ Ua, u16* __restrict__ Ub, u16* __restrict__ Uc, u16* __restrict__ Ud,
    float* __restrict__ Yacc)
{
  const int b = blockIdx.y;
  const int t = threadIdx.x;
  const int w = t >> 6, lane = t & 63;
  const int col = lane & 15, quad = lane >> 4;
  const int ij0 = blockIdx.x*64;

  __shared__ uint32_t lsb[4][32*SJ32];
  __shared__ float lsf[64*SJF];

  // ---- hoisted loads: wave w owns e-tile [16w,16w+16); all Wb frags once ----
  short8 wa[10][2];
  #pragma unroll
  for (int s = 0; s < 10; s++){
    const u16* wp = Wb + (size_t)((s*64 + w*16 + col)*64 + quad*8);
    wa[s][0] = *(const short8*)wp;
    wa[s][1] = *(const short8*)(wp + 32);
  }
  short8 xb[4][2];
  #pragma unroll
  for (int sj = 0; sj < 4; sj++){
    const u16* xp = Xt + ((size_t)(b*16384 + ij0 + sj*16 + col))*64 + quad*8;
    xb[sj][0] = *(const short8*)xp;
    xb[sj][1] = *(const short8*)(xp + 32);
  }
  float a_s[4], t_s[4], rjv[4];
  #pragma unroll
  for (int sj = 0; sj < 4; sj++){
    int ij = ij0 + sj*16 + col;
    a_s[sj] = A[b*16384 + ij];
    t_s[sj] = AAt[b*16384 + ij];
    rjv[sj] = rA[b*128 + (ij & 127)];
  }
  const float riv = rA[b*128 + (ij0 >> 7)];

  #pragma unroll
  for (int g = 0; g < 5; g++){
    const int s0_tab[5]  = {0, 2, 4, 5, 6};
    const int nsl_tab[5] = {2, 2, 1, 1, 4};
    const int s0 = s0_tab[g], nsl = nsl_tab[g];
    #pragma unroll
    for (int sj = 0; sj < 4; sj++){
      f32x4 acc[4];
      #pragma unroll
      for (int s = 0; s < 4; s++) acc[s] = (f32x4){0.f,0.f,0.f,0.f};
      #pragma unroll
      for (int s = 0; s < 4; s++){
        if (s >= nsl) break;
        acc[s] = MFMA16(wa[s0+s][0], xb[sj][0], acc[s]);
        acc[s] = MFMA16(wa[s0+s][1], xb[sj][1], acc[s]);
      }
      if (g < 4){
        float v[4];
        #pragma unroll
        for (int r = 0; r < 4; r++){
          if (g == 2 || g == 3) v[r] = acc[0][r]*a_s[sj];
          else                  v[r] = acc[0][r]*a_s[sj] + acc[1][r];
        }
        uint32_t p0 = (uint32_t)f2b(v[0]) | ((uint32_t)f2b(v[1]) << 16);
        uint32_t p1 = (uint32_t)f2b(v[2]) | ((uint32_t)f2b(v[3]) << 16);
        int ep = w*8 + quad*2;
        lsb[g][ep*SJ32 + sj*16 + col] = p0;
        lsb[g][(ep + 1)*SJ32 + sj*16 + col] = p1;
      } else {
        #pragma unroll
        for (int r = 0; r < 4; r++){
          float v = acc[0][r]*t_s[sj] + acc[1][r]*riv + acc[2][r]*rjv[sj] + acc[3][r];
          lsf[(w*16 + quad*4 + r)*SJF + sj*16 + col] = v;
        }
      }
    }
  }
  __syncthreads();   // the ONLY barrier

  const int eo = t >> 2, seg = t & 3;
  const int ep = eo >> 1, sh = (eo & 1)*16;
  #pragma unroll
  for (int g = 0; g < 4; g++){
    const uint32_t* lp = &lsb[g][ep*SJ32 + seg*16];
    short8 v0, v1;
    #pragma unroll
    for (int k = 0; k < 8; k++){
      v0[k] = (short)((lp[k]   >> sh) & 0xffffu);
      v1[k] = (short)((lp[8+k] >> sh) & 0xffffu);
    }
    u16* U = (g==0)?Ua:(g==1)?Ub:(g==2)?Uc:Ud;
    u16* dst = U + ((size_t)(b*64 + eo) << 14) + ij0 + seg*16;
    *(short8*)dst = v0;
    *(short8*)(dst + 8) = v1;
  }
  {
    const float* fp = &lsf[eo*SJF + seg*16];
    float* dst = Yacc + ((size_t)(b*64 + eo) << 14) + ij0 + seg*16;
    #pragma unroll
    for (int q = 0; q < 4; q++)
      *(float4*)(dst + q*4) = make_float4(fp[q*4], fp[q*4+1], fp[q*4+2], fp[q*4+3]);
  }
}

// ---- fused: four A-products (MFMA) + Yacc + broadcast + bias + sigmoid/reduce ----
__global__ __launch_bounds__(256) void k_tne(const u16* __restrict__ ATb,
    const u16* __restrict__ UaT, const u16* __restrict__ UbT,
    const u16* __restrict__ Uc, const u16* __restrict__ Ud,
    const float* __restrict__ Yacc, const float* __restrict__ W,
    const float* __restrict__ RM, const float* __restrict__ CM,
    const float* __restrict__ RX, const float* __restrict__ CXv,
    const float* __restrict__ bias, u16* __restrict__ Xout, float* __restrict__ acc4, int last)
{
  const int nh = blockIdx.x, be = blockIdx.y;
  const int b = be >> 6, e = be & 63;
  const int t = threadIdx.x, wave = t >> 6, lane = t & 63;
  const int col = lane & 15, quad = lane >> 4;
  const int m0 = (wave >> 1)*64;
  const int n0 = nh*64 + (wave & 1)*32;

  __shared__ float radd[128], cadd[128];
  __shared__ uint32_t stg[64*68];
  __shared__ float red[4];

  if (t < 128){
    int i = t; float s = 0.f;
    for (int d = 0; d < ND; d++){
      int v = (b*ND + d)*NN + i;
      s += W[(640 + d)*64 + e]*RM[v] + W[(704 + d)*64 + e]*CM[v]
         + W[(768 + d)*64 + e]*RX[v] + W[(832 + d)*64 + e]*CXv[v];
    }
    radd[i] = s;
  } else {
    int j = t - 128; float s = 0.f;
    for (int d = 0; d < ND; d++){
      int v = (b*ND + d)*NN + j;
      s += W[(896 + d)*64 + e]*RM[v] + W[(960 + d)*64 + e]*CM[v]
         + W[(1024 + d)*64 + e]*RX[v] + W[(1088 + d)*64 + e]*CXv[v];
    }
    cadd[j] = s;
  }

  f32x4 acc[4][2];
  #pragma unroll
  for (int mt = 0; mt < 4; mt++)
    #pragma unroll
    for (int nt = 0; nt < 2; nt++)
      acc[mt][nt] = (f32x4){0.f,0.f,0.f,0.f};

  const u16* at = ATb + ((size_t)b << 14);
  const u16* sa_t[4] = {UaT + ((size_t)be << 14), at, Uc + ((size_t)be << 14), at};
  const u16* rb_t[4] = {at, UbT + ((size_t)be << 14), at, Ud + ((size_t)be << 14)};

  #pragma unroll
  for (int f = 0; f < 4; f++){
    const u16* sa = sa_t[f];
    const u16* rb = rb_t[f];
    #pragma unroll
    for (int kq = 0; kq < 4; kq++){
      int k0 = kq*32 + quad*8;
      short8 bf0 = *(const short8*)(rb + (n0 + col)*128 + k0);
      short8 bf1 = *(const short8*)(rb + (n0 + 16 + col)*128 + k0);
      #pragma unroll
      for (int mt = 0; mt < 4; mt++){
        short8 af = *(const short8*)(sa + (m0 + mt*16 + col)*128 + k0);
        acc[mt][0] = MFMA16(af, bf0, acc[mt][0]);
        acc[mt][1] = MFMA16(af, bf1, acc[mt][1]);
      }
    }
  }
  __syncthreads();   // radd/cadd ready

  const float bv = bias[e];
  const float* Y = Yacc + ((size_t)be << 14);
  if (!last){
    #pragma unroll
    for (int mt = 0; mt < 4; mt++)
      #pragma unroll
      for (int nt = 0; nt < 2; nt++)
        #pragma unroll
        for (int rp = 0; rp < 2; rp++){
          uint32_t p = 0;
          #pragma unroll
          for (int h = 0; h < 2; h++){
            int r = rp*2 + h;
            int row = m0 + mt*16 + quad*4 + r;
            int cn = n0 + nt*16 + col;
            float v = acc[mt][nt][r] + Y[row*128 + cn] + radd[row] + cadd[cn] + bv;
            v = 1.f/(1.f + __expf(-v));
            p |= ((uint32_t)f2b(v)) << (16*h);
          }
          int ipair = (m0 + mt*16 + quad*4) >> 1;
          stg[(ipair + rp)*68 + (wave & 1)*32 + nt*16 + col] = p;
        }
    __syncthreads();
    const uint32_t* lp = &stg[(t >> 2)*68 + (t & 1)*32];
    const int sh = ((t >> 1) & 1)*16;
    u16* dst = Xout + ((size_t)be << 14) + (size_t)(t >> 1)*128 + nh*64 + (t & 1)*32;
    #pragma unroll
    for (int q2 = 0; q2 < 4; q2++){
      short8 v;
      #pragma unroll
      for (int k = 0; k < 8; k++) v[k] = (short)((lp[q2*8 + k] >> sh) & 0xffffu);
      *(short8*)(dst + q2*8) = v;
    }
  } else {
    float loc = 0.f;
    #pragma unroll
    for (int mt = 0; mt < 4; mt++)
      #pragma unroll
      for (int nt = 0; nt < 2; nt++)
        #pragma unroll
        for (int r = 0; r < 4; r++){
          int row = m0 + mt*16 + quad*4 + r;
          int cn = n0 + nt*16 + col;
          loc += acc[mt][nt][r] + Y[row*128 + cn] + radd[row] + cadd[cn] + bv;
        }
    for (int off = 32; off > 0; off >>= 1) loc += __shfl_down(loc, off, 64);
    if (lane == 0) red[wave] = loc;
    __syncthreads();
    if (t == 0) atomicAdd(&acc4[b], red[0] + red[1] + red[2] + red[3]);
  }
}

__global__ void k_finish(const float* __restrict__ acc4, const int* __restrict__ flag,
                         void* __restrict__ out){
  int b = threadIdx.x;
  if (b >= NB) return;
  float v = acc4[b] * (1.0f/1048576.0f);
  if (*flag) ((float*)out)[b] = v;
  else       ((u16*)out)[b] = f2b(v);
}

extern "C" void kernel_launch(void* const* d_in, const int* in_sizes, int n_in,
                              void* d_out, int out_size, void* d_ws, size_t ws_size,
                              hipStream_t stream)
{
  const void* x   = d_in[0];
  const void* ew  = d_in[1];
  const void* c1  = d_in[2];
  const void* b1  = d_in[3];
  const void* c2  = d_in[4];
  const void* b2  = d_in[5];
  const int* ei  = (const int*)d_in[6];
  const int* bat = (const int*)d_in[7];
  const int E = in_sizes[1];

  char* wsb = (char*)d_ws;
  float* A    = (float*)(wsb + OFF_A);
  float* acc4 = (float*)(wsb + OFF_ACC);
  float* AAt  = (float*)(wsb + OFF_AAT);
  float* rA   = (float*)(wsb + OFF_RA);
  float* W    = (float*)(wsb + OFF_W);
  float* RM   = (float*)(wsb + OFF_RM);
  float* CM   = (float*)(wsb + OFF_CM);
  float* RX   = (float*)(wsb + OFF_RX);
  float* CXv  = (float*)(wsb + OFF_CX);
  int*   flag = (int*)(wsb + OFF_FLAG);
  float* bfv  = (float*)(wsb + OFF_BF);
  u16* ATb = (u16*)(wsb + OFF_ATB);
  u16* Wb  = (u16*)(wsb + OFF_WB);
  u16* X2  = (u16*)(wsb + OFF_X2);
  u16* Xt  = (u16*)(wsb + OFF_XT);
  u16* Ua  = (u16*)(wsb + OFF_UA);
  u16* Ub  = (u16*)(wsb + OFF_UB);
  u16* Uc  = (u16*)(wsb + OFF_UC);
  u16* Ud  = (u16*)(wsb + OFF_UD);
  u16* UaT = (u16*)(wsb + OFF_UAT2);
  u16* UbT = (u16*)(wsb + OFF_UBT2);
  float* Yacc = (float*)(wsb + OFF_YACC);
  float* xf   = (float*)(wsb + OFF_XF);
  float* ewf  = (float*)(wsb + OFF_EWF);
  float* cf   = (float*)(wsb + OFF_CF);

  hipMemsetAsync(wsb, 0, OFF_AAT, stream);
  hipMemsetAsync(wsb + OFF_FLAG, 0, 256, stream);

  k_detect<<<dim3(1), dim3(256), 0, stream>>>((const u16*)x, flag);
  k_convert<<<dim3(737), dim3(256), 0, stream>>>(x, ew, c1, c2, b1, b2, flag, xf, ewf, cf, bfv);
  k_scatter<<<dim3((E + 255)/256), dim3(256), 0, stream>>>(ei, bat, ewf, A, E);
  k_rA<<<dim3(NB), dim3(128), 0, stream>>>(A, rA);
  k_AAt<<<dim3(8, NB), dim3(256), 0, stream>>>(A, AAt);
  k_at<<<dim3(NB), dim3(256), 0, stream>>>(A, ATb);
  k_makeXt1<<<dim3(NMAT/8/256), dim3(256), 0, stream>>>(xf, Xt);
  k_buildW<<<dim3(576), dim3(256), 0, stream>>>(cf, W, Wb);

  for (int L = 0; L < 2; L++){
    const float* Wl = W + (size_t)L*1152*64;
    const u16*  Wbl = Wb + (size_t)L*10*64*64;
    if (L == 1)
      k_xt<<<dim3(256, NB), dim3(256), 0, stream>>>(X2, Xt);
    k_rowcol<<<dim3(64, NB), dim3(256), 0, stream>>>(Xt, A, RM, CM, RX, CXv);
    k_mix<<<dim3(256, NB), dim3(256), 0, stream>>>(Xt, A, AAt, rA, Wbl, Ua, Ub, Uc, Ud, Yacc);
    k_ut2<<<dim3(256), dim3(256), 0, stream>>>(Ua, Ub, UaT, UbT);
    k_tne<<<dim3(2, 256), dim3(256), 0, stream>>>(ATb, UaT, UbT, Uc, Ud, Yacc, Wl,
                                                  RM, CM, RX, CXv, bfv + L*64, X2, acc4, L);
  }
  k_finish<<<dim3(1), dim3(64), 0, stream>>>(acc4, flag, d_out);
}

// Round 9
// 255.557 us; speedup vs baseline: 1.4100x; 1.1387x over previous
//
#include <hip/hip_runtime.h>
#include <stdint.h>

typedef unsigned short u16;
using short8 = __attribute__((ext_vector_type(8))) short;
using f32x4  = __attribute__((ext_vector_type(4))) float;

#define NB 4
#define NN 128
#define NF 32
#define ND 64
#define NMAT (NB*ND*NN*NN)   // 4,194,304

// ---- workspace byte offsets (R8 map; FLAG region now unused) ----
#define OFF_A     0u
#define OFF_ACC   262144u
#define OFF_AAT   262400u
#define OFF_RA    524544u
#define OFF_W     526592u
#define OFF_RM    1116416u
#define OFF_CM    1247488u
#define OFF_RX    1378560u
#define OFF_CX    1509632u
#define OFF_BF    1640960u
#define OFF_ATB   1641472u
#define OFF_WB    1772544u
#define OFF_X2    1936384u
#define OFF_XT    10324992u
#define OFF_UA    18713600u
#define OFF_UB    27102208u
#define OFF_UC    35490816u
#define OFF_UD    43879424u
#define OFF_YACC  52268032u
#define OFF_XF    (OFF_YACC)
#define OFF_EWF   (OFF_YACC + 65536u)
#define OFF_CF    (OFF_YACC + 98304u)
#define OFF_UAT2  OFF_XT
#define OFF_UBT2  OFF_UA

__device__ __forceinline__ float b2f(u16 v){
  union { uint32_t u; float f; } x; x.u = ((uint32_t)v) << 16; return x.f;
}
__device__ __forceinline__ u16 f2b(float f){
  union { uint32_t u; float f2; } x; x.f2 = f;
  uint32_t u = x.u;
  return (u16)((u + 0x7FFFu + ((u >> 16) & 1u)) >> 16);
}

#define MFMA16(a,b,c) __builtin_amdgcn_mfma_f32_16x16x32_bf16((a),(b),(c),0,0,0)

__device__ __constant__ signed char dR1[18] = {0,9,1,10,2,3,4,13,14,19,5,7,15,18,6,8,16,17};
__device__ __constant__ signed char dR2[18] = {-1,11,-1,12,-1,-1,-1,-1,-1,-1,-1,-1,-1,-1,-1,-1,-1,-1};

// ---- convert with per-block local dtype detect (scan x16[0:1024]) ----
__global__ void k_convert(const void* __restrict__ xs, const void* __restrict__ ews,
                          const void* __restrict__ c1s, const void* __restrict__ c2s,
                          const void* __restrict__ b1s, const void* __restrict__ b2s,
                          float* __restrict__ xf, float* __restrict__ ewf,
                          float* __restrict__ cf, float* __restrict__ bfv){
  __shared__ int flg;
  const u16* x16 = (const u16*)xs;
  if (threadIdx.x == 0) flg = 0;
  __syncthreads();
  int hit = 0;
  for (int k = threadIdx.x; k < 1024; k += 256){
    u16 u = x16[k];
    if (((u >> 7) & 0xFF) >= 0x90) hit = 1;
  }
  if (hit) flg = 1;
  __syncthreads();
  const int isf = flg;

  int t = blockIdx.x*256 + threadIdx.x;
  if (t >= 188544) return;
  const void* src; int idx; float* dst;
  if (t < 16384)      { src = xs;  idx = t;          dst = xf + idx; }
  else if (t < 24576) { src = ews; idx = t - 16384;  dst = ewf + idx; }
  else if (t < 106496){ src = c1s; idx = t - 24576;  dst = cf + idx; }
  else if (t < 188416){ src = c2s; idx = t - 106496; dst = cf + 81920 + idx; }
  else if (t < 188480){ src = b1s; idx = t - 188416; dst = bfv + idx; }
  else                { src = b2s; idx = t - 188480; dst = bfv + 64 + idx; }
  float v = isf ? ((const float*)src)[idx] : b2f(((const u16*)src)[idx]);
  *dst = v;
}

// ---- fused setup: scatter (bx<32, grid-stride) | makeXt1 (32..2079) | buildW (2080..2655) ----
__global__ void k_setup(const int* __restrict__ ei, const int* __restrict__ bat,
                        const float* __restrict__ ewf, float* __restrict__ A, int E,
                        const float* __restrict__ xf, u16* __restrict__ Xt,
                        const float* __restrict__ cf, float* __restrict__ W,
                        u16* __restrict__ Wb){
  const int bx = blockIdx.x;
  if (bx < 32){
    for (int t = bx*256 + threadIdx.x; t < E; t += 32*256){
      int s = ei[t], dnode = ei[E + t];
      int g = bat[s];
      int r = s - g*NN, c = dnode - g*NN;
      atomicAdd(&A[(g*NN + r)*NN + c], ewf[t]);
    }
  } else if (bx < 32 + 2048){
    int gid = (bx - 32)*256 + threadIdx.x;
    if (gid >= NMAT/8) return;
    int d0 = (gid & 7)*8;
    int ij = (gid >> 3) & 16383;
    int b  = gid >> 17;
    int i = ij >> 7, j = ij & 127;
    const float* src = (d0 < NF) ? &xf[(b*NN + i)*NF + d0] : &xf[(b*NN + j)*NF + (d0 - NF)];
    float4 f0 = *(const float4*)src;
    float4 f1 = *(const float4*)(src + 4);
    short8 v;
    v[0]=(short)f2b(f0.x); v[1]=(short)f2b(f0.y); v[2]=(short)f2b(f0.z); v[3]=(short)f2b(f0.w);
    v[4]=(short)f2b(f1.x); v[5]=(short)f2b(f1.y); v[6]=(short)f2b(f1.z); v[7]=(short)f2b(f1.w);
    *(short8*)(Xt + ((size_t)(b*16384 + ij))*64 + d0) = v;
  } else {
    int gl = (bx - 2080)*256 + threadIdx.x;
    if (gl >= 2*1152*64) return;
    int L = gl / (1152*64);
    int rem = gl - L*1152*64;
    int row = rem >> 6, e = rem & 63;
    int slot = row >> 6, d = row & 63;
    const float* cc = cf + L*81920;
    int base = (d*64 + e)*20;
    float v = cc[base + dR1[slot]];
    if (dR2[slot] >= 0) v += cc[base + dR2[slot]];
    float scale = (slot == 9) ? 1.0f : (1.0f/128.0f);
    v *= scale;
    W[gl] = v;
    if (slot < 10)
      Wb[(((size_t)L*10 + slot)*64 + e)*64 + d] = f2b(v);
  }
}

// ---- fused A-processing: iq<8 = AAt slices | iq==8 = ATb transpose | iq==9 = rA ----
__global__ __launch_bounds__(256) void k_prepA(const float* __restrict__ A, float* __restrict__ AAt,
                                               u16* __restrict__ ATb, float* __restrict__ rA){
  const int iq = blockIdx.x, b = blockIdx.y;
  const int t = threadIdx.x;
  if (iq < 8){
    int j = t & 127, ih = t >> 7;
    const float* Ab = A + b*NN*NN;
    float acc[8] = {0,0,0,0,0,0,0,0};
    for (int k = 0; k < NN; k++){
      float aj = Ab[j*NN + k];
      #pragma unroll
      for (int ii = 0; ii < 8; ii++){
        int i = iq*16 + ih*8 + ii;
        acc[ii] += Ab[i*NN + k] * aj;
      }
    }
    #pragma unroll
    for (int ii = 0; ii < 8; ii++){
      int i = iq*16 + ih*8 + ii;
      AAt[(b*NN + i)*NN + j] = acc[ii];
    }
  } else if (iq == 8){
    __shared__ float lds[128][129];
    for (int l = 0; l < 64; l++){
      int idx = l*256 + t;
      lds[idx >> 7][idx & 127] = A[b*16384 + idx];
    }
    __syncthreads();
    for (int l = 0; l < 64; l++){
      int idx = l*256 + t;
      int r = idx >> 7, c = idx & 127;
      ATb[b*16384 + idx] = f2b(lds[c][r]);
    }
  } else {
    if (t < 128){
      const float* Ab = A + (b*NN + t)*NN;
      float s = 0.f;
      for (int j = 0; j < NN; j++) s += Ab[j];
      rA[b*NN + t] = s;
    }
  }
}

// ---- X2[b][e][ij] -> Xt[b][ij][e] via LDS tiles ----
__global__ __launch_bounds__(256) void k_xt(const u16* __restrict__ X, u16* __restrict__ Xt){
  int b = blockIdx.y;
  int ij0 = blockIdx.x*64;
  __shared__ u16 lds[64][65];
  int t = threadIdx.x;
  #pragma unroll
  for (int l = 0; l < 2; l++){
    int idx = l*2048 + t*8;
    int d = idx >> 6, c = idx & 63;
    const u16* p = X + ((size_t)(b*64 + d))*16384 + ij0 + c;
    short8 v = *(const short8*)p;
    #pragma unroll
    for (int k = 0; k < 8; k++) lds[d][c + k] = (u16)v[k];
  }
  __syncthreads();
  #pragma unroll
  for (int l = 0; l < 2; l++){
    int idx = l*2048 + t*8;
    int r = idx >> 6, c = idx & 63;
    short8 v;
    #pragma unroll
    for (int k = 0; k < 8; k++) v[k] = (short)lds[c + k][r];
    *(short8*)(Xt + ((size_t)(b*16384 + ij0 + r))*64 + c) = v;
  }
}

// ---- both transposes in one block: Ua->UaT(Xt region), Ub->UbT(Ua region) ----
__global__ __launch_bounds__(256) void k_ut2(const u16* __restrict__ Ua, const u16* __restrict__ Ub,
                                             u16* __restrict__ UaT, u16* __restrict__ UbT){
  int be = blockIdx.x;
  __shared__ u16 lds[128][129];
  int t = threadIdx.x;
  for (int h = 0; h < 2; h++){
    const u16* src = (h ? Ub : Ua) + ((size_t)be << 14);
    u16* dst = (h ? UbT : UaT) + ((size_t)be << 14);
    if (h) __syncthreads();
    #pragma unroll
    for (int l = 0; l < 8; l++){
      int idx = l*2048 + t*8;
      int r = idx >> 7, c = idx & 127;
      short8 v = *(const short8*)(src + r*128 + c);
      #pragma unroll
      for (int k = 0; k < 8; k++) lds[r][c + k] = (u16)v[k];
    }
    __syncthreads();
    #pragma unroll
    for (int l = 0; l < 8; l++){
      int idx = l*2048 + t*8;
      int r = idx >> 7, c = idx & 127;
      short8 v;
      #pragma unroll
      for (int k = 0; k < 8; k++) v[k] = (short)lds[c + k][r];
      *(short8*)(dst + r*128 + c) = v;
    }
  }
}

#define SJ32 72
#define SJF  69

// ---- fused: mix (bx<256, R8-verbatim body) | rowcol (bx>=256) ----
__global__ __launch_bounds__(256) void k_mixrow(const u16* __restrict__ Xt, const float* __restrict__ A,
    const float* __restrict__ AAt, const float* __restrict__ rA, const u16* __restrict__ Wb,
    u16* __restrict__ Ua, u16* __restrict__ Ub, u16* __restrict__ Uc, u16* __restrict__ Ud,
    float* __restrict__ Yacc,
    float* __restrict__ RM, float* __restrict__ CM,
    float* __restrict__ RX, float* __restrict__ CXv)
{
  const int b = blockIdx.y;
  const int t = threadIdx.x;

  if (blockIdx.x >= 256){
    // ---- rowcol (R8-verbatim) ----
    int d = t & 63;
    int task = (blockIdx.x - 256)*4 + (t >> 6);
    float sm = 0.f, sx = 0.f;
    if (task < 128){
      int i = task;
      for (int j = 0; j < 128; j++){
        float xv = b2f(Xt[((size_t)(b*16384 + i*128 + j))*64 + d]);
        float av = A[b*16384 + i*128 + j];
        sm += xv*av; sx += xv;
      }
      RM[(b*64 + d)*128 + i] = sm;
      RX[(b*64 + d)*128 + i] = sx;
    } else {
      int j = task - 128;
      for (int i = 0; i < 128; i++){
        float xv = b2f(Xt[((size_t)(b*16384 + i*128 + j))*64 + d]);
        float av = A[b*16384 + i*128 + j];
        sm += xv*av; sx += xv;
      }
      CM[(b*64 + d)*128 + j] = sm;
      CXv[(b*64 + d)*128 + j] = sx;
    }
    return;
  }

  // ---- mix (R8-verbatim) ----
  const int w = t >> 6, lane = t & 63;
  const int col = lane & 15, quad = lane >> 4;
  const int ij0 = blockIdx.x*64;

  __shared__ uint32_t lsb[4][32*SJ32];
  __shared__ float lsf[64*SJF];

  short8 wa[10][2];
  #pragma unroll
  for (int s = 0; s < 10; s++){
    const u16* wp = Wb + (size_t)((s*64 + w*16 + col)*64 + quad*8);
    wa[s][0] = *(const short8*)wp;
    wa[s][1] = *(const short8*)(wp + 32);
  }
  short8 xb[4][2];
  #pragma unroll
  for (int sj = 0; sj < 4; sj++){
    const u16* xp = Xt + ((size_t)(b*16384 + ij0 + sj*16 + col))*64 + quad*8;
    xb[sj][0] = *(const short8*)xp;
    xb[sj][1] = *(const short8*)(xp + 32);
  }
  float a_s[4], t_s[4], rjv[4];
  #pragma unroll
  for (int sj = 0; sj < 4; sj++){
    int ij = ij0 + sj*16 + col;
    a_s[sj] = A[b*16384 + ij];
    t_s[sj] = AAt[b*16384 + ij];
    rjv[sj] = rA[b*128 + (ij & 127)];
  }
  const float riv = rA[b*128 + (ij0 >> 7)];

  #pragma unroll
  for (int g = 0; g < 5; g++){
    const int s0_tab[5]  = {0, 2, 4, 5, 6};
    const int nsl_tab[5] = {2, 2, 1, 1, 4};
    const int s0 = s0_tab[g], nsl = nsl_tab[g];
    #pragma unroll
    for (int sj = 0; sj < 4; sj++){
      f32x4 acc[4];
      #pragma unroll
      for (int s = 0; s < 4; s++) acc[s] = (f32x4){0.f,0.f,0.f,0.f};
      #pragma unroll
      for (int s = 0; s < 4; s++){
        if (s >= nsl) break;
        acc[s] = MFMA16(wa[s0+s][0], xb[sj][0], acc[s]);
        acc[s] = MFMA16(wa[s0+s][1], xb[sj][1], acc[s]);
      }
      if (g < 4){
        float v[4];
        #pragma unroll
        for (int r = 0; r < 4; r++){
          if (g == 2 || g == 3) v[r] = acc[0][r]*a_s[sj];
          else                  v[r] = acc[0][r]*a_s[sj] + acc[1][r];
        }
        uint32_t p0 = (uint32_t)f2b(v[0]) | ((uint32_t)f2b(v[1]) << 16);
        uint32_t p1 = (uint32_t)f2b(v[2]) | ((uint32_t)f2b(v[3]) << 16);
        int ep = w*8 + quad*2;
        lsb[g][ep*SJ32 + sj*16 + col] = p0;
        lsb[g][(ep + 1)*SJ32 + sj*16 + col] = p1;
      } else {
        #pragma unroll
        for (int r = 0; r < 4; r++){
          float v = acc[0][r]*t_s[sj] + acc[1][r]*riv + acc[2][r]*rjv[sj] + acc[3][r];
          lsf[(w*16 + quad*4 + r)*SJF + sj*16 + col] = v;
        }
      }
    }
  }
  __syncthreads();

  const int eo = t >> 2, seg = t & 3;
  const int ep = eo >> 1, sh = (eo & 1)*16;
  #pragma unroll
  for (int g = 0; g < 4; g++){
    const uint32_t* lp = &lsb[g][ep*SJ32 + seg*16];
    short8 v0, v1;
    #pragma unroll
    for (int k = 0; k < 8; k++){
      v0[k] = (short)((lp[k]   >> sh) & 0xffffu);
      v1[k] = (short)((lp[8+k] >> sh) & 0xffffu);
    }
    u16* U = (g==0)?Ua:(g==1)?Ub:(g==2)?Uc:Ud;
    u16* dst = U + ((size_t)(b*64 + eo) << 14) + ij0 + seg*16;
    *(short8*)dst = v0;
    *(short8*)(dst + 8) = v1;
  }
  {
    const float* fp = &lsf[eo*SJF + seg*16];
    float* dst = Yacc + ((size_t)(b*64 + eo) << 14) + ij0 + seg*16;
    #pragma unroll
    for (int q = 0; q < 4; q++)
      *(float4*)(dst + q*4) = make_float4(fp[q*4], fp[q*4+1], fp[q*4+2], fp[q*4+3]);
  }
}

// ---- fused: four A-products (MFMA) + Yacc + broadcast + bias + sigmoid/reduce (R8-verbatim) ----
__global__ __launch_bounds__(256) void k_tne(const u16* __restrict__ ATb,
    const u16* __restrict__ UaT, const u16* __restrict__ UbT,
    const u16* __restrict__ Uc, const u16* __restrict__ Ud,
    const float* __restrict__ Yacc, const float* __restrict__ W,
    const float* __restrict__ RM, const float* __restrict__ CM,
    const float* __restrict__ RX, const float* __restrict__ CXv,
    const float* __restrict__ bias, u16* __restrict__ Xout, float* __restrict__ acc4, int last)
{
  const int nh = blockIdx.x, be = blockIdx.y;
  const int b = be >> 6, e = be & 63;
  const int t = threadIdx.x, wave = t >> 6, lane = t & 63;
  const int col = lane & 15, quad = lane >> 4;
  const int m0 = (wave >> 1)*64;
  const int n0 = nh*64 + (wave & 1)*32;

  __shared__ float radd[128], cadd[128];
  __shared__ uint32_t stg[64*68];
  __shared__ float red[4];

  if (t < 128){
    int i = t; float s = 0.f;
    for (int d = 0; d < ND; d++){
      int v = (b*ND + d)*NN + i;
      s += W[(640 + d)*64 + e]*RM[v] + W[(704 + d)*64 + e]*CM[v]
         + W[(768 + d)*64 + e]*RX[v] + W[(832 + d)*64 + e]*CXv[v];
    }
    radd[i] = s;
  } else {
    int j = t - 128; float s = 0.f;
    for (int d = 0; d < ND; d++){
      int v = (b*ND + d)*NN + j;
      s += W[(896 + d)*64 + e]*RM[v] + W[(960 + d)*64 + e]*CM[v]
         + W[(1024 + d)*64 + e]*RX[v] + W[(1088 + d)*64 + e]*CXv[v];
    }
    cadd[j] = s;
  }

  f32x4 acc[4][2];
  #pragma unroll
  for (int mt = 0; mt < 4; mt++)
    #pragma unroll
    for (int nt = 0; nt < 2; nt++)
      acc[mt][nt] = (f32x4){0.f,0.f,0.f,0.f};

  const u16* at = ATb + ((size_t)b << 14);
  const u16* sa_t[4] = {UaT + ((size_t)be << 14), at, Uc + ((size_t)be << 14), at};
  const u16* rb_t[4] = {at, UbT + ((size_t)be << 14), at, Ud + ((size_t)be << 14)};

  #pragma unroll
  for (int f = 0; f < 4; f++){
    const u16* sa = sa_t[f];
    const u16* rb = rb_t[f];
    #pragma unroll
    for (int kq = 0; kq < 4; kq++){
      int k0 = kq*32 + quad*8;
      short8 bf0 = *(const short8*)(rb + (n0 + col)*128 + k0);
      short8 bf1 = *(const short8*)(rb + (n0 + 16 + col)*128 + k0);
      #pragma unroll
      for (int mt = 0; mt < 4; mt++){
        short8 af = *(const short8*)(sa + (m0 + mt*16 + col)*128 + k0);
        acc[mt][0] = MFMA16(af, bf0, acc[mt][0]);
        acc[mt][1] = MFMA16(af, bf1, acc[mt][1]);
      }
    }
  }
  __syncthreads();   // radd/cadd ready

  const float bv = bias[e];
  const float* Y = Yacc + ((size_t)be << 14);
  if (!last){
    #pragma unroll
    for (int mt = 0; mt < 4; mt++)
      #pragma unroll
      for (int nt = 0; nt < 2; nt++)
        #pragma unroll
        for (int rp = 0; rp < 2; rp++){
          uint32_t p = 0;
          #pragma unroll
          for (int h = 0; h < 2; h++){
            int r = rp*2 + h;
            int row = m0 + mt*16 + quad*4 + r;
            int cn = n0 + nt*16 + col;
            float v = acc[mt][nt][r] + Y[row*128 + cn] + radd[row] + cadd[cn] + bv;
            v = 1.f/(1.f + __expf(-v));
            p |= ((uint32_t)f2b(v)) << (16*h);
          }
          int ipair = (m0 + mt*16 + quad*4) >> 1;
          stg[(ipair + rp)*68 + (wave & 1)*32 + nt*16 + col] = p;
        }
    __syncthreads();
    const uint32_t* lp = &stg[(t >> 2)*68 + (t & 1)*32];
    const int sh = ((t >> 1) & 1)*16;
    u16* dst = Xout + ((size_t)be << 14) + (size_t)(t >> 1)*128 + nh*64 + (t & 1)*32;
    #pragma unroll
    for (int q2 = 0; q2 < 4; q2++){
      short8 v;
      #pragma unroll
      for (int k = 0; k < 8; k++) v[k] = (short)((lp[q2*8 + k] >> sh) & 0xffffu);
      *(short8*)(dst + q2*8) = v;
    }
  } else {
    float loc = 0.f;
    #pragma unroll
    for (int mt = 0; mt < 4; mt++)
      #pragma unroll
      for (int nt = 0; nt < 2; nt++)
        #pragma unroll
        for (int r = 0; r < 4; r++){
          int row = m0 + mt*16 + quad*4 + r;
          int cn = n0 + nt*16 + col;
          loc += acc[mt][nt][r] + Y[row*128 + cn] + radd[row] + cadd[cn] + bv;
        }
    for (int off = 32; off > 0; off >>= 1) loc += __shfl_down(loc, off, 64);
    if (lane == 0) red[wave] = loc;
    __syncthreads();
    if (t == 0) atomicAdd(&acc4[b], red[0] + red[1] + red[2] + red[3]);
  }
}

// ---- finish with inline dtype detect ----
__global__ void k_finish(const float* __restrict__ acc4, const u16* __restrict__ x16,
                         void* __restrict__ out){
  __shared__ int flg;
  int t = threadIdx.x;   // 64 threads
  if (t == 0) flg = 0;
  __syncthreads();
  int hit = 0;
  for (int k = t; k < 512; k += 64){
    u16 u = x16[k];
    if (((u >> 7) & 0xFF) >= 0x90) hit = 1;
  }
  if (hit) flg = 1;
  __syncthreads();
  if (t < NB){
    float v = acc4[t] * (1.0f/1048576.0f);
    if (flg) ((float*)out)[t] = v;
    else     ((u16*)out)[t] = f2b(v);
  }
}

extern "C" void kernel_launch(void* const* d_in, const int* in_sizes, int n_in,
                              void* d_out, int out_size, void* d_ws, size_t ws_size,
                              hipStream_t stream)
{
  const void* x   = d_in[0];
  const void* ew  = d_in[1];
  const void* c1  = d_in[2];
  const void* b1  = d_in[3];
  const void* c2  = d_in[4];
  const void* b2  = d_in[5];
  const int* ei  = (const int*)d_in[6];
  const int* bat = (const int*)d_in[7];
  const int E = in_sizes[1];

  char* wsb = (char*)d_ws;
  float* A    = (float*)(wsb + OFF_A);
  float* acc4 = (float*)(wsb + OFF_ACC);
  float* AAt  = (float*)(wsb + OFF_AAT);
  float* rA   = (float*)(wsb + OFF_RA);
  float* W    = (float*)(wsb + OFF_W);
  float* RM   = (float*)(wsb + OFF_RM);
  float* CM   = (float*)(wsb + OFF_CM);
  float* RX   = (float*)(wsb + OFF_RX);
  float* CXv  = (float*)(wsb + OFF_CX);
  float* bfv  = (float*)(wsb + OFF_BF);
  u16* ATb = (u16*)(wsb + OFF_ATB);
  u16* Wb  = (u16*)(wsb + OFF_WB);
  u16* X2  = (u16*)(wsb + OFF_X2);
  u16* Xt  = (u16*)(wsb + OFF_XT);
  u16* Ua  = (u16*)(wsb + OFF_UA);
  u16* Ub  = (u16*)(wsb + OFF_UB);
  u16* Uc  = (u16*)(wsb + OFF_UC);
  u16* Ud  = (u16*)(wsb + OFF_UD);
  u16* UaT = (u16*)(wsb + OFF_UAT2);
  u16* UbT = (u16*)(wsb + OFF_UBT2);
  float* Yacc = (float*)(wsb + OFF_YACC);
  float* xf   = (float*)(wsb + OFF_XF);
  float* ewf  = (float*)(wsb + OFF_EWF);
  float* cf   = (float*)(wsb + OFF_CF);

  hipMemsetAsync(wsb, 0, OFF_AAT, stream);   // zero A + acc4

  k_convert<<<dim3(737), dim3(256), 0, stream>>>(x, ew, c1, c2, b1, b2, xf, ewf, cf, bfv);
  k_setup<<<dim3(2656), dim3(256), 0, stream>>>(ei, bat, ewf, A, E, xf, Xt, cf, W, Wb);
  k_prepA<<<dim3(10, NB), dim3(256), 0, stream>>>(A, AAt, ATb, rA);

  for (int L = 0; L < 2; L++){
    const float* Wl = W + (size_t)L*1152*64;
    const u16*  Wbl = Wb + (size_t)L*10*64*64;
    if (L == 1)
      k_xt<<<dim3(256, NB), dim3(256), 0, stream>>>(X2, Xt);
    k_mixrow<<<dim3(320, NB), dim3(256), 0, stream>>>(Xt, A, AAt, rA, Wbl,
                                                      Ua, Ub, Uc, Ud, Yacc, RM, CM, RX, CXv);
    k_ut2<<<dim3(256), dim3(256), 0, stream>>>(Ua, Ub, UaT, UbT);
    k_tne<<<dim3(2, 256), dim3(256), 0, stream>>>(ATb, UaT, UbT, Uc, Ud, Yacc, Wl,
                                                  RM, CM, RX, CXv, bfv + L*64, X2, acc4, L);
  }
  k_finish<<<dim3(1), dim3(64), 0, stream>>>(acc4, (const u16*)x, d_out);
}

// Round 10
// 236.424 us; speedup vs baseline: 1.5241x; 1.0809x over previous
//
#include <hip/hip_runtime.h>
#include <stdint.h>

typedef unsigned short u16;
using short8 = __attribute__((ext_vector_type(8))) short;
using f32x4  = __attribute__((ext_vector_type(4))) float;

#define NB 4
#define NN 128
#define NF 32
#define ND 64
#define NMAT (NB*ND*NN*NN)   // 4,194,304

// ---- workspace byte offsets ----
#define OFF_A     0u
#define OFF_ACC   262144u
#define OFF_AAT   262400u
#define OFF_RA    524544u
#define OFF_W     526592u
#define OFF_RM    1116416u
#define OFF_CM    1247488u
#define OFF_RX    1378560u
#define OFF_CX    1509632u
#define OFF_BF    1640960u
#define OFF_ATB   1641472u
#define OFF_WB    1772544u
#define OFF_X2    1936384u
#define OFF_XT    10324992u
#define OFF_UA    18713600u
#define OFF_UB    27102208u
#define OFF_UC    35490816u
#define OFF_UD    43879424u
#define OFF_YACC  52268032u
#define OFF_XF    (OFF_YACC)
#define OFF_EWF   (OFF_YACC + 65536u)
#define OFF_CF    (OFF_YACC + 98304u)

__device__ __forceinline__ float b2f(u16 v){
  union { uint32_t u; float f; } x; x.u = ((uint32_t)v) << 16; return x.f;
}
__device__ __forceinline__ u16 f2b(float f){
  union { uint32_t u; float f2; } x; x.f2 = f;
  uint32_t u = x.u;
  return (u16)((u + 0x7FFFu + ((u >> 16) & 1u)) >> 16);
}

#define MFMA16(a,b,c) __builtin_amdgcn_mfma_f32_16x16x32_bf16((a),(b),(c),0,0,0)

__device__ __constant__ signed char dR1[18] = {0,9,1,10,2,3,4,13,14,19,5,7,15,18,6,8,16,17};
__device__ __constant__ signed char dR2[18] = {-1,11,-1,12,-1,-1,-1,-1,-1,-1,-1,-1,-1,-1,-1,-1,-1,-1};

// ---- convert with per-block local dtype detect ----
__global__ void k_convert(const void* __restrict__ xs, const void* __restrict__ ews,
                          const void* __restrict__ c1s, const void* __restrict__ c2s,
                          const void* __restrict__ b1s, const void* __restrict__ b2s,
                          float* __restrict__ xf, float* __restrict__ ewf,
                          float* __restrict__ cf, float* __restrict__ bfv){
  __shared__ int flg;
  const u16* x16 = (const u16*)xs;
  if (threadIdx.x == 0) flg = 0;
  __syncthreads();
  int hit = 0;
  for (int k = threadIdx.x; k < 1024; k += 256){
    u16 u = x16[k];
    if (((u >> 7) & 0xFF) >= 0x90) hit = 1;
  }
  if (hit) flg = 1;
  __syncthreads();
  const int isf = flg;

  int t = blockIdx.x*256 + threadIdx.x;
  if (t >= 188544) return;
  const void* src; int idx; float* dst;
  if (t < 16384)      { src = xs;  idx = t;          dst = xf + idx; }
  else if (t < 24576) { src = ews; idx = t - 16384;  dst = ewf + idx; }
  else if (t < 106496){ src = c1s; idx = t - 24576;  dst = cf + idx; }
  else if (t < 188416){ src = c2s; idx = t - 106496; dst = cf + 81920 + idx; }
  else if (t < 188480){ src = b1s; idx = t - 188416; dst = bfv + idx; }
  else                { src = b2s; idx = t - 188480; dst = bfv + 64 + idx; }
  float v = isf ? ((const float*)src)[idx] : b2f(((const u16*)src)[idx]);
  *dst = v;
}

// ---- fused setup: scatter | makeXt1 | buildW ----
__global__ void k_setup(const int* __restrict__ ei, const int* __restrict__ bat,
                        const float* __restrict__ ewf, float* __restrict__ A, int E,
                        const float* __restrict__ xf, u16* __restrict__ Xt,
                        const float* __restrict__ cf, float* __restrict__ W,
                        u16* __restrict__ Wb){
  const int bx = blockIdx.x;
  if (bx < 32){
    for (int t = bx*256 + threadIdx.x; t < E; t += 32*256){
      int s = ei[t], dnode = ei[E + t];
      int g = bat[s];
      int r = s - g*NN, c = dnode - g*NN;
      atomicAdd(&A[(g*NN + r)*NN + c], ewf[t]);
    }
  } else if (bx < 32 + 2048){
    int gid = (bx - 32)*256 + threadIdx.x;
    if (gid >= NMAT/8) return;
    int d0 = (gid & 7)*8;
    int ij = (gid >> 3) & 16383;
    int b  = gid >> 17;
    int i = ij >> 7, j = ij & 127;
    const float* src = (d0 < NF) ? &xf[(b*NN + i)*NF + d0] : &xf[(b*NN + j)*NF + (d0 - NF)];
    float4 f0 = *(const float4*)src;
    float4 f1 = *(const float4*)(src + 4);
    short8 v;
    v[0]=(short)f2b(f0.x); v[1]=(short)f2b(f0.y); v[2]=(short)f2b(f0.z); v[3]=(short)f2b(f0.w);
    v[4]=(short)f2b(f1.x); v[5]=(short)f2b(f1.y); v[6]=(short)f2b(f1.z); v[7]=(short)f2b(f1.w);
    *(short8*)(Xt + ((size_t)(b*16384 + ij))*64 + d0) = v;
  } else {
    int gl = (bx - 2080)*256 + threadIdx.x;
    if (gl >= 2*1152*64) return;
    int L = gl / (1152*64);
    int rem = gl - L*1152*64;
    int row = rem >> 6, e = rem & 63;
    int slot = row >> 6, d = row & 63;
    const float* cc = cf + L*81920;
    int base = (d*64 + e)*20;
    float v = cc[base + dR1[slot]];
    if (dR2[slot] >= 0) v += cc[base + dR2[slot]];
    float scale = (slot == 9) ? 1.0f : (1.0f/128.0f);
    v *= scale;
    W[gl] = v;
    if (slot < 10)
      Wb[(((size_t)L*10 + slot)*64 + e)*64 + d] = f2b(v);
  }
}

// ---- fused A-processing: iq<8 = AAt slices | iq==8 = ATb transpose | iq==9 = rA ----
__global__ __launch_bounds__(256) void k_prepA(const float* __restrict__ A, float* __restrict__ AAt,
                                               u16* __restrict__ ATb, float* __restrict__ rA){
  const int iq = blockIdx.x, b = blockIdx.y;
  const int t = threadIdx.x;
  if (iq < 8){
    int j = t & 127, ih = t >> 7;
    const float* Ab = A + b*NN*NN;
    float acc[8] = {0,0,0,0,0,0,0,0};
    for (int k = 0; k < NN; k++){
      float aj = Ab[j*NN + k];
      #pragma unroll
      for (int ii = 0; ii < 8; ii++){
        int i = iq*16 + ih*8 + ii;
        acc[ii] += Ab[i*NN + k] * aj;
      }
    }
    #pragma unroll
    for (int ii = 0; ii < 8; ii++){
      int i = iq*16 + ih*8 + ii;
      AAt[(b*NN + i)*NN + j] = acc[ii];
    }
  } else if (iq == 8){
    __shared__ float lds[128][129];
    for (int l = 0; l < 64; l++){
      int idx = l*256 + t;
      lds[idx >> 7][idx & 127] = A[b*16384 + idx];
    }
    __syncthreads();
    for (int l = 0; l < 64; l++){
      int idx = l*256 + t;
      int r = idx >> 7, c = idx & 127;
      ATb[b*16384 + idx] = f2b(lds[c][r]);
    }
  } else {
    if (t < 128){
      const float* Ab = A + (b*NN + t)*NN;
      float s = 0.f;
      for (int j = 0; j < NN; j++) s += Ab[j];
      rA[b*NN + t] = s;
    }
  }
}

// ---- X2[b][e][ij] -> Xt[b][ij][e] via LDS tiles ----
__global__ __launch_bounds__(256) void k_xt(const u16* __restrict__ X, u16* __restrict__ Xt){
  int b = blockIdx.y;
  int ij0 = blockIdx.x*64;
  __shared__ u16 lds[64][65];
  int t = threadIdx.x;
  #pragma unroll
  for (int l = 0; l < 2; l++){
    int idx = l*2048 + t*8;
    int d = idx >> 6, c = idx & 63;
    const u16* p = X + ((size_t)(b*64 + d))*16384 + ij0 + c;
    short8 v = *(const short8*)p;
    #pragma unroll
    for (int k = 0; k < 8; k++) lds[d][c + k] = (u16)v[k];
  }
  __syncthreads();
  #pragma unroll
  for (int l = 0; l < 2; l++){
    int idx = l*2048 + t*8;
    int r = idx >> 6, c = idx & 63;
    short8 v;
    #pragma unroll
    for (int k = 0; k < 8; k++) v[k] = (short)lds[c + k][r];
    *(short8*)(Xt + ((size_t)(b*16384 + ij0 + r))*64 + c) = v;
  }
}

#define SJ32 72
#define SJF  69

// ---- fused: mix (bx<256) | rowcol (bx>=256)  — R9-verbatim ----
__global__ __launch_bounds__(256) void k_mixrow(const u16* __restrict__ Xt, const float* __restrict__ A,
    const float* __restrict__ AAt, const float* __restrict__ rA, const u16* __restrict__ Wb,
    u16* __restrict__ Ua, u16* __restrict__ Ub, u16* __restrict__ Uc, u16* __restrict__ Ud,
    float* __restrict__ Yacc,
    float* __restrict__ RM, float* __restrict__ CM,
    float* __restrict__ RX, float* __restrict__ CXv)
{
  const int b = blockIdx.y;
  const int t = threadIdx.x;

  if (blockIdx.x >= 256){
    int d = t & 63;
    int task = (blockIdx.x - 256)*4 + (t >> 6);
    float sm = 0.f, sx = 0.f;
    if (task < 128){
      int i = task;
      for (int j = 0; j < 128; j++){
        float xv = b2f(Xt[((size_t)(b*16384 + i*128 + j))*64 + d]);
        float av = A[b*16384 + i*128 + j];
        sm += xv*av; sx += xv;
      }
      RM[(b*64 + d)*128 + i] = sm;
      RX[(b*64 + d)*128 + i] = sx;
    } else {
      int j = task - 128;
      for (int i = 0; i < 128; i++){
        float xv = b2f(Xt[((size_t)(b*16384 + i*128 + j))*64 + d]);
        float av = A[b*16384 + i*128 + j];
        sm += xv*av; sx += xv;
      }
      CM[(b*64 + d)*128 + j] = sm;
      CXv[(b*64 + d)*128 + j] = sx;
    }
    return;
  }

  const int w = t >> 6, lane = t & 63;
  const int col = lane & 15, quad = lane >> 4;
  const int ij0 = blockIdx.x*64;

  __shared__ uint32_t lsb[4][32*SJ32];
  __shared__ float lsf[64*SJF];

  short8 wa[10][2];
  #pragma unroll
  for (int s = 0; s < 10; s++){
    const u16* wp = Wb + (size_t)((s*64 + w*16 + col)*64 + quad*8);
    wa[s][0] = *(const short8*)wp;
    wa[s][1] = *(const short8*)(wp + 32);
  }
  short8 xb[4][2];
  #pragma unroll
  for (int sj = 0; sj < 4; sj++){
    const u16* xp = Xt + ((size_t)(b*16384 + ij0 + sj*16 + col))*64 + quad*8;
    xb[sj][0] = *(const short8*)xp;
    xb[sj][1] = *(const short8*)(xp + 32);
  }
  float a_s[4], t_s[4], rjv[4];
  #pragma unroll
  for (int sj = 0; sj < 4; sj++){
    int ij = ij0 + sj*16 + col;
    a_s[sj] = A[b*16384 + ij];
    t_s[sj] = AAt[b*16384 + ij];
    rjv[sj] = rA[b*128 + (ij & 127)];
  }
  const float riv = rA[b*128 + (ij0 >> 7)];

  #pragma unroll
  for (int g = 0; g < 5; g++){
    const int s0_tab[5]  = {0, 2, 4, 5, 6};
    const int nsl_tab[5] = {2, 2, 1, 1, 4};
    const int s0 = s0_tab[g], nsl = nsl_tab[g];
    #pragma unroll
    for (int sj = 0; sj < 4; sj++){
      f32x4 acc[4];
      #pragma unroll
      for (int s = 0; s < 4; s++) acc[s] = (f32x4){0.f,0.f,0.f,0.f};
      #pragma unroll
      for (int s = 0; s < 4; s++){
        if (s >= nsl) break;
        acc[s] = MFMA16(wa[s0+s][0], xb[sj][0], acc[s]);
        acc[s] = MFMA16(wa[s0+s][1], xb[sj][1], acc[s]);
      }
      if (g < 4){
        float v[4];
        #pragma unroll
        for (int r = 0; r < 4; r++){
          if (g == 2 || g == 3) v[r] = acc[0][r]*a_s[sj];
          else                  v[r] = acc[0][r]*a_s[sj] + acc[1][r];
        }
        uint32_t p0 = (uint32_t)f2b(v[0]) | ((uint32_t)f2b(v[1]) << 16);
        uint32_t p1 = (uint32_t)f2b(v[2]) | ((uint32_t)f2b(v[3]) << 16);
        int ep = w*8 + quad*2;
        lsb[g][ep*SJ32 + sj*16 + col] = p0;
        lsb[g][(ep + 1)*SJ32 + sj*16 + col] = p1;
      } else {
        #pragma unroll
        for (int r = 0; r < 4; r++){
          float v = acc[0][r]*t_s[sj] + acc[1][r]*riv + acc[2][r]*rjv[sj] + acc[3][r];
          lsf[(w*16 + quad*4 + r)*SJF + sj*16 + col] = v;
        }
      }
    }
  }
  __syncthreads();

  const int eo = t >> 2, seg = t & 3;
  const int ep = eo >> 1, sh = (eo & 1)*16;
  #pragma unroll
  for (int g = 0; g < 4; g++){
    const uint32_t* lp = &lsb[g][ep*SJ32 + seg*16];
    short8 v0, v1;
    #pragma unroll
    for (int k = 0; k < 8; k++){
      v0[k] = (short)((lp[k]   >> sh) & 0xffffu);
      v1[k] = (short)((lp[8+k] >> sh) & 0xffffu);
    }
    u16* U = (g==0)?Ua:(g==1)?Ub:(g==2)?Uc:Ud;
    u16* dst = U + ((size_t)(b*64 + eo) << 14) + ij0 + seg*16;
    *(short8*)dst = v0;
    *(short8*)(dst + 8) = v1;
  }
  {
    const float* fp = &lsf[eo*SJF + seg*16];
    float* dst = Yacc + ((size_t)(b*64 + eo) << 14) + ij0 + seg*16;
    #pragma unroll
    for (int q = 0; q < 4; q++)
      *(float4*)(dst + q*4) = make_float4(fp[q*4], fp[q*4+1], fp[q*4+2], fp[q*4+3]);
  }
}

#define SLT 68   // uint32 stride for in-kernel transpose staging (b128 reads 2-way max)

// ---- fused: in-LDS transposes + four A-products + Yacc + broadcast + bias + sigmoid/reduce ----
__global__ __launch_bounds__(256) void k_tne(const u16* __restrict__ ATb,
    const u16* __restrict__ Ua, const u16* __restrict__ Ub,
    const u16* __restrict__ Uc, const u16* __restrict__ Ud,
    const float* __restrict__ Yacc, const float* __restrict__ W,
    const float* __restrict__ RM, const float* __restrict__ CM,
    const float* __restrict__ RX, const float* __restrict__ CXv,
    const float* __restrict__ bias, u16* __restrict__ Xout, float* __restrict__ acc4, int last)
{
  const int nh = blockIdx.x, be = blockIdx.y;
  const int b = be >> 6, e = be & 63;
  const int t = threadIdx.x, wave = t >> 6, lane = t & 63;
  const int col = lane & 15, quad = lane >> 4;
  const int m0 = (wave >> 1)*64;
  const int n0 = nh*64 + (wave & 1)*32;
  const int nb0 = nh*64;

  __shared__ uint32_t uls[128*SLT];   // uat (packed bf16 pairs); stg aliases after MFMA
  __shared__ uint32_t ubl[64*SLT];    // ubt (packed bf16 pairs)
  __shared__ float radd[128], cadd[128];
  __shared__ float red[4];

  // broadcast-term vectors for this e
  if (t < 128){
    int i = t; float s = 0.f;
    for (int d = 0; d < ND; d++){
      int v = (b*ND + d)*NN + i;
      s += W[(640 + d)*64 + e]*RM[v] + W[(704 + d)*64 + e]*CM[v]
         + W[(768 + d)*64 + e]*RX[v] + W[(832 + d)*64 + e]*CXv[v];
    }
    radd[i] = s;
  } else {
    int j = t - 128; float s = 0.f;
    for (int d = 0; d < ND; d++){
      int v = (b*ND + d)*NN + j;
      s += W[(896 + d)*64 + e]*RM[v] + W[(960 + d)*64 + e]*CM[v]
         + W[(1024 + d)*64 + e]*RX[v] + W[(1088 + d)*64 + e]*CXv[v];
    }
    cadd[j] = s;
  }

  // stage Ua (full slab) and Ub (nh column-block) transposed+pair-packed into LDS
  const u16* ua = Ua + ((size_t)be << 14);
  const u16* ub = Ub + ((size_t)be << 14);
  {
    const int kp = t >> 2;               // 0..63
    #pragma unroll
    for (int it = 0; it < 4; it++){
      int mo = it*4 + (t & 3);           // 0..15
      short8 r0 = *(const short8*)(ua + (2*kp)*128 + mo*8);
      short8 r1 = *(const short8*)(ua + (2*kp + 1)*128 + mo*8);
      #pragma unroll
      for (int x = 0; x < 8; x++)
        uls[(mo*8 + x)*SLT + kp] = ((uint32_t)(u16)r0[x]) | (((uint32_t)(u16)r1[x]) << 16);
    }
    #pragma unroll
    for (int it = 0; it < 2; it++){
      int no = it*4 + (t & 3);           // 0..7
      short8 r0 = *(const short8*)(ub + (2*kp)*128 + nb0 + no*8);
      short8 r1 = *(const short8*)(ub + (2*kp + 1)*128 + nb0 + no*8);
      #pragma unroll
      for (int x = 0; x < 8; x++)
        ubl[(no*8 + x)*SLT + kp] = ((uint32_t)(u16)r0[x]) | (((uint32_t)(u16)r1[x]) << 16);
    }
  }
  __syncthreads();   // uat/ubt + radd/cadd ready

  f32x4 acc[4][2];
  #pragma unroll
  for (int mt = 0; mt < 4; mt++)
    #pragma unroll
    for (int nt = 0; nt < 2; nt++)
      acc[mt][nt] = (f32x4){0.f,0.f,0.f,0.f};

  const u16* at = ATb + ((size_t)b << 14);
  // cache ATb n-side fragments (used by f0 and f2)
  short8 at_n[4][2];
  #pragma unroll
  for (int kq = 0; kq < 4; kq++){
    int k0 = kq*32 + quad*8;
    at_n[kq][0] = *(const short8*)(at + (n0 + col)*128 + k0);
    at_n[kq][1] = *(const short8*)(at + (n0 + 16 + col)*128 + k0);
  }

  // f0: Ua^T · A   (sa from LDS uat)
  #pragma unroll
  for (int kq = 0; kq < 4; kq++){
    int kd = kq*16 + quad*4;
    #pragma unroll
    for (int mt = 0; mt < 4; mt++){
      short8 af = *(const short8*)&uls[(m0 + mt*16 + col)*SLT + kd];
      acc[mt][0] = MFMA16(af, at_n[kq][0], acc[mt][0]);
      acc[mt][1] = MFMA16(af, at_n[kq][1], acc[mt][1]);
    }
  }
  // f1: A^T · Ub   (rb from LDS ubt)
  #pragma unroll
  for (int kq = 0; kq < 4; kq++){
    int k0 = kq*32 + quad*8, kd = kq*16 + quad*4;
    short8 bf0 = *(const short8*)&ubl[((wave & 1)*32 + 0*16 + col)*SLT + kd];
    short8 bf1 = *(const short8*)&ubl[((wave & 1)*32 + 1*16 + col)*SLT + kd];
    #pragma unroll
    for (int mt = 0; mt < 4; mt++){
      short8 af = *(const short8*)(at + (m0 + mt*16 + col)*128 + k0);
      acc[mt][0] = MFMA16(af, bf0, acc[mt][0]);
      acc[mt][1] = MFMA16(af, bf1, acc[mt][1]);
    }
  }
  // f2: Uc · A
  {
    const u16* uc = Uc + ((size_t)be << 14);
    #pragma unroll
    for (int kq = 0; kq < 4; kq++){
      int k0 = kq*32 + quad*8;
      #pragma unroll
      for (int mt = 0; mt < 4; mt++){
        short8 af = *(const short8*)(uc + (m0 + mt*16 + col)*128 + k0);
        acc[mt][0] = MFMA16(af, at_n[kq][0], acc[mt][0]);
        acc[mt][1] = MFMA16(af, at_n[kq][1], acc[mt][1]);
      }
    }
  }
  // f3: (Ud · A)^T
  {
    const u16* ud = Ud + ((size_t)be << 14);
    #pragma unroll
    for (int kq = 0; kq < 4; kq++){
      int k0 = kq*32 + quad*8;
      short8 bf0 = *(const short8*)(ud + (n0 + col)*128 + k0);
      short8 bf1 = *(const short8*)(ud + (n0 + 16 + col)*128 + k0);
      #pragma unroll
      for (int mt = 0; mt < 4; mt++){
        short8 af = *(const short8*)(at + (m0 + mt*16 + col)*128 + k0);
        acc[mt][0] = MFMA16(af, bf0, acc[mt][0]);
        acc[mt][1] = MFMA16(af, bf1, acc[mt][1]);
      }
    }
  }
  __syncthreads();   // all LDS frag reads done -> uls reusable as stg

  uint32_t* stg = uls;
  const float bv = bias[e];
  const float* Y = Yacc + ((size_t)be << 14);
  if (!last){
    #pragma unroll
    for (int mt = 0; mt < 4; mt++)
      #pragma unroll
      for (int nt = 0; nt < 2; nt++)
        #pragma unroll
        for (int rp = 0; rp < 2; rp++){
          uint32_t p = 0;
          #pragma unroll
          for (int h = 0; h < 2; h++){
            int r = rp*2 + h;
            int row = m0 + mt*16 + quad*4 + r;
            int cn = n0 + nt*16 + col;
            float v = acc[mt][nt][r] + Y[row*128 + cn] + radd[row] + cadd[cn] + bv;
            v = 1.f/(1.f + __expf(-v));
            p |= ((uint32_t)f2b(v)) << (16*h);
          }
          int ipair = (m0 + mt*16 + quad*4) >> 1;
          stg[(ipair + rp)*SLT + (wave & 1)*32 + nt*16 + col] = p;
        }
    __syncthreads();
    const uint32_t* lp = &stg[(t >> 2)*SLT + (t & 1)*32];
    const int sh = ((t >> 1) & 1)*16;
    u16* dst = Xout + ((size_t)be << 14) + (size_t)(t >> 1)*128 + nh*64 + (t & 1)*32;
    #pragma unroll
    for (int q2 = 0; q2 < 4; q2++){
      short8 v;
      #pragma unroll
      for (int k = 0; k < 8; k++) v[k] = (short)((lp[q2*8 + k] >> sh) & 0xffffu);
      *(short8*)(dst + q2*8) = v;
    }
  } else {
    float loc = 0.f;
    #pragma unroll
    for (int mt = 0; mt < 4; mt++)
      #pragma unroll
      for (int nt = 0; nt < 2; nt++)
        #pragma unroll
        for (int r = 0; r < 4; r++){
          int row = m0 + mt*16 + quad*4 + r;
          int cn = n0 + nt*16 + col;
          loc += acc[mt][nt][r] + Y[row*128 + cn] + radd[row] + cadd[cn] + bv;
        }
    for (int off = 32; off > 0; off >>= 1) loc += __shfl_down(loc, off, 64);
    if (lane == 0) red[wave] = loc;
    __syncthreads();
    if (t == 0) atomicAdd(&acc4[b], red[0] + red[1] + red[2] + red[3]);
  }
}

// ---- finish with inline dtype detect ----
__global__ void k_finish(const float* __restrict__ acc4, const u16* __restrict__ x16,
                         void* __restrict__ out){
  __shared__ int flg;
  int t = threadIdx.x;   // 64 threads
  if (t == 0) flg = 0;
  __syncthreads();
  int hit = 0;
  for (int k = t; k < 512; k += 64){
    u16 u = x16[k];
    if (((u >> 7) & 0xFF) >= 0x90) hit = 1;
  }
  if (hit) flg = 1;
  __syncthreads();
  if (t < NB){
    float v = acc4[t] * (1.0f/1048576.0f);
    if (flg) ((float*)out)[t] = v;
    else     ((u16*)out)[t] = f2b(v);
  }
}

extern "C" void kernel_launch(void* const* d_in, const int* in_sizes, int n_in,
                              void* d_out, int out_size, void* d_ws, size_t ws_size,
                              hipStream_t stream)
{
  const void* x   = d_in[0];
  const void* ew  = d_in[1];
  const void* c1  = d_in[2];
  const void* b1  = d_in[3];
  const void* c2  = d_in[4];
  const void* b2  = d_in[5];
  const int* ei  = (const int*)d_in[6];
  const int* bat = (const int*)d_in[7];
  const int E = in_sizes[1];

  char* wsb = (char*)d_ws;
  float* A    = (float*)(wsb + OFF_A);
  float* acc4 = (float*)(wsb + OFF_ACC);
  float* AAt  = (float*)(wsb + OFF_AAT);
  float* rA   = (float*)(wsb + OFF_RA);
  float* W    = (float*)(wsb + OFF_W);
  float* RM   = (float*)(wsb + OFF_RM);
  float* CM   = (float*)(wsb + OFF_CM);
  float* RX   = (float*)(wsb + OFF_RX);
  float* CXv  = (float*)(wsb + OFF_CX);
  float* bfv  = (float*)(wsb + OFF_BF);
  u16* ATb = (u16*)(wsb + OFF_ATB);
  u16* Wb  = (u16*)(wsb + OFF_WB);
  u16* X2  = (u16*)(wsb + OFF_X2);
  u16* Xt  = (u16*)(wsb + OFF_XT);
  u16* Ua  = (u16*)(wsb + OFF_UA);
  u16* Ub  = (u16*)(wsb + OFF_UB);
  u16* Uc  = (u16*)(wsb + OFF_UC);
  u16* Ud  = (u16*)(wsb + OFF_UD);
  float* Yacc = (float*)(wsb + OFF_YACC);
  float* xf   = (float*)(wsb + OFF_XF);
  float* ewf  = (float*)(wsb + OFF_EWF);
  float* cf   = (float*)(wsb + OFF_CF);

  hipMemsetAsync(wsb, 0, OFF_AAT, stream);   // zero A + acc4

  k_convert<<<dim3(737), dim3(256), 0, stream>>>(x, ew, c1, c2, b1, b2, xf, ewf, cf, bfv);
  k_setup<<<dim3(2656), dim3(256), 0, stream>>>(ei, bat, ewf, A, E, xf, Xt, cf, W, Wb);
  k_prepA<<<dim3(10, NB), dim3(256), 0, stream>>>(A, AAt, ATb, rA);

  for (int L = 0; L < 2; L++){
    const float* Wl = W + (size_t)L*1152*64;
    const u16*  Wbl = Wb + (size_t)L*10*64*64;
    if (L == 1)
      k_xt<<<dim3(256, NB), dim3(256), 0, stream>>>(X2, Xt);
    k_mixrow<<<dim3(320, NB), dim3(256), 0, stream>>>(Xt, A, AAt, rA, Wbl,
                                                      Ua, Ub, Uc, Ud, Yacc, RM, CM, RX, CXv);
    k_tne<<<dim3(2, 256), dim3(256), 0, stream>>>(ATb, Ua, Ub, Uc, Ud, Yacc, Wl,
                                                  RM, CM, RX, CXv, bfv + L*64, X2, acc4, L);
  }
  k_finish<<<dim3(1), dim3(64), 0, stream>>>(acc4, (const u16*)x, d_out);
}